// Round 12
// baseline (335.265 us; speedup 1.0000x reference)
//
#include <hip/hip_runtime.h>
#include <math.h>
#include <cfloat>

// ---------------- problem constants ----------------
#define G_    50
#define N0_   1000
#define NEDGE 200000
#define EPG_  (NEDGE/G_)   // 4000 edges per graph (contiguous slots)
#define P_    10
#define FEAT_ 1036
#define NHID_ 128
#define GDIM_ 32
#define K0_   200
#define K1_   40
#define K2_   8
#define M0_   (G_*N0_)     // 50000
#define M1_   (G_*K0_)     // 10000
#define M2_   (G_*K1_)     // 2000

#define KPAD_ 1088         // 1036 padded to multiple of 64
#define MPAD0_ 50048       // mult of 128
#define MPAD1_ 10112       // mult of 128
#define MPAD2_ 2048        // mult of 128

typedef __attribute__((ext_vector_type(8))) short s16x8;
typedef __attribute__((ext_vector_type(4))) float f32x4;

__device__ __forceinline__ unsigned f2bf1(float f) {   // bf16 bits, RNE
  unsigned u = __float_as_uint(f);
  return (u + 0x7FFFu + ((u >> 16) & 1u)) >> 16;
}
__device__ __forceinline__ unsigned packbf(float a, float b) {
  return f2bf1(a) | (f2bf1(b) << 16);
}

__device__ __forceinline__ void gload_lds16(const void* g, void* l) {
  __builtin_amdgcn_global_load_lds((const __attribute__((address_space(1))) void*)g,
                                   (__attribute__((address_space(3))) void*)l, 16, 0, 0);
}

// ---------------- kernels ----------------

// row-major colmax
__global__ void colmax_kernel(const float* __restrict__ x, int* __restrict__ scale_i) {
  int tid = threadIdx.x, wave = tid >> 6, lane = tid & 63;
  float mx[12];
#pragma unroll
  for (int j = 0; j < 12; j++) mx[j] = 0.f;
  for (int r = blockIdx.x * 256 + tid; r < M0_; r += gridDim.x * 256) {
    const float4* p = (const float4*)(x + (size_t)r * FEAT_);
    float4 a = p[0], b = p[1], c = p[2];
    mx[0] = fmaxf(mx[0], a.x); mx[1] = fmaxf(mx[1], a.y);
    mx[2] = fmaxf(mx[2], a.z); mx[3] = fmaxf(mx[3], a.w);
    mx[4] = fmaxf(mx[4], b.x); mx[5] = fmaxf(mx[5], b.y);
    mx[6] = fmaxf(mx[6], b.z); mx[7] = fmaxf(mx[7], b.w);
    mx[8] = fmaxf(mx[8], c.x); mx[9] = fmaxf(mx[9], c.y);
    mx[10] = fmaxf(mx[10], c.z); mx[11] = fmaxf(mx[11], c.w);
  }
#pragma unroll
  for (int off = 32; off > 0; off >>= 1)
#pragma unroll
    for (int j = 0; j < 12; j++) mx[j] = fmaxf(mx[j], __shfl_down(mx[j], off));
  __shared__ float red[4][12];
  if (lane == 0)
#pragma unroll
    for (int j = 0; j < 12; j++) red[wave][j] = mx[j];
  __syncthreads();
  if (tid < 12) {
    float m = fmaxf(fmaxf(red[0][tid], red[1][tid]), fmaxf(red[2][tid], red[3][tid]));
    atomicMax(scale_i + tid, __float_as_int(m));
  }
}

__global__ void build_wt0_kernel(const float* __restrict__ wl, const float* __restrict__ wr,
                                 const int* __restrict__ scale_i, unsigned short* __restrict__ WT) {
  int idx = blockIdx.x * blockDim.x + threadIdx.x;
  if (idx >= 256 * KPAD_) return;
  int c = idx / KPAD_, j = idx % KPAD_;
  float w = 0.f;
  if (j < FEAT_) {
    w = (c < NHID_) ? wl[j * NHID_ + c] : wr[j * NHID_ + (c - NHID_)];
    if (j < 12) w *= 1.0f / __int_as_float(scale_i[j]);
  }
  WT[idx] = (unsigned short)f2bf1(w);
}

__global__ void build_wt12_kernel(const float* __restrict__ wl1, const float* __restrict__ wr1,
                                  const float* __restrict__ wl2, const float* __restrict__ wr2,
                                  unsigned short* __restrict__ WTA, unsigned short* __restrict__ WTB) {
  int idx = blockIdx.x * blockDim.x + threadIdx.x;
  if (idx >= 2 * 256 * 128) return;
  int l = idx >> 15, r = idx & 32767;
  int c = r >> 7, j = r & 127;
  const float* wl = l ? wl2 : wl1;
  const float* wr = l ? wr2 : wr1;
  float w = (c < NHID_) ? wl[j * NHID_ + c] : wr[j * NHID_ + (c - NHID_)];
  (l ? WTB : WTA)[r] = (unsigned short)f2bf1(w);
}

// C[M x 256] = A @ WT^T.  128x256 tile (full N); 4 waves 2x2, each 64x128.
// BK=64 as two 32-wide panels.  Pipelined: A(t+1) issued to regs and B(t+1)
// staged into a DOUBLE-buffered LDS before the MFMA of step t; A regs are
// packed/written after barrier 1 (issue-early / write-late, T14).
template <bool AF32>
__global__ __launch_bounds__(256) void mfma_gemm_kernel(const float* __restrict__ Af,
                                                        const unsigned short* __restrict__ Ab,
                                                        const unsigned short* __restrict__ WT,
                                                        float* __restrict__ C, int M,
                                                        int lda, int ldb, int kvalid, int ksteps) {
  __shared__ unsigned short As[2 * 128 * 32];        // single A tile, panel kk at +kk*4096
  __shared__ unsigned short Bs[2][2 * 256 * 32];     // dbuf B, panel kk at +kk*8192
  const int bm = blockIdx.x * 128;
  const int tid = threadIdx.x, wave = tid >> 6, lane = tid & 63;
  const int wr = wave >> 1, wc = wave & 1;
  const int lhi = lane >> 4, llo = lane & 15;
  const int arow = tid >> 1, ahalf = tid & 1;        // 32 k-elems per thread
  f32x4 acc[4][8] = {};

  float fA[32];
  uint4 vA[4];

  auto loadA = [&](int st) {    // issue global loads into regs
    const int k0 = st * 64;
    int gr = bm + arow;
    int gk = k0 + ahalf * 32;
    if (AF32) {
      if (gr < M && gk + 32 <= kvalid) {
        const float4* ap = (const float4*)(Af + (size_t)gr * lda + gk);
#pragma unroll
        for (int j = 0; j < 8; j++) {
          float4 v = ap[j];
          fA[4 * j] = v.x; fA[4 * j + 1] = v.y; fA[4 * j + 2] = v.z; fA[4 * j + 3] = v.w;
        }
      } else {
        const float* ap = Af + (size_t)gr * lda + gk;
#pragma unroll
        for (int j = 0; j < 32; j++)
          fA[j] = (gr < M && gk + j < kvalid) ? ap[j] : 0.f;
      }
    } else {
      const uint4* ap = (const uint4*)(Ab + (size_t)gr * lda + gk);
#pragma unroll
      for (int j = 0; j < 4; j++) vA[j] = ap[j];
    }
  };
  auto writeA = [&]() {         // pack + ds_write into the single A tile
    unsigned short* dstp = As + ahalf * 4096 + arow * 32;
    if (AF32) {
#pragma unroll
      for (int j = 0; j < 4; j++) {
        uint4 p;
        p.x = packbf(fA[8 * j + 0], fA[8 * j + 1]); p.y = packbf(fA[8 * j + 2], fA[8 * j + 3]);
        p.z = packbf(fA[8 * j + 4], fA[8 * j + 5]); p.w = packbf(fA[8 * j + 6], fA[8 * j + 7]);
        *(uint4*)(dstp + j * 8) = p;
      }
    } else {
#pragma unroll
      for (int j = 0; j < 4; j++) ((uint4*)dstp)[j] = vA[j];
    }
  };
  auto stageB = [&](int st, int b) {
    const int k0 = st * 64;
#pragma unroll
    for (int it = 0; it < 8; it++) {
      int c = it * 256 + wave * 64 + lane;         // 0..2047, LDS-linear
      int kk = c >> 10, r = (c >> 2) & 255, cb = c & 3;
      gload_lds16(WT + (size_t)r * ldb + k0 + kk * 32 + cb * 8, &Bs[b][(size_t)c * 8]);
    }
  };

  // prologue: step 0 fully staged
  loadA(0);
  stageB(0, 0);
  writeA();
  __syncthreads();

  for (int st = 0; st < ksteps; st++) {
    const int bbuf = st & 1;
    const bool more = (st + 1 < ksteps);
    if (more) {
      loadA(st + 1);            // A latency overlaps MFMA below
      stageB(st + 1, bbuf ^ 1); // B latency overlaps MFMA below (other buffer)
    }
#pragma unroll
    for (int kk = 0; kk < 2; kk++) {
      s16x8 a[4], b[8];
#pragma unroll
      for (int mt = 0; mt < 4; mt++)
        a[mt] = *(const s16x8*)&As[kk * 4096 + (wr * 64 + mt * 16 + llo) * 32 + lhi * 8];
#pragma unroll
      for (int nt = 0; nt < 8; nt++)
        b[nt] = *(const s16x8*)&Bs[bbuf][kk * 8192 + (wc * 128 + nt * 16 + llo) * 32 + lhi * 8];
#pragma unroll
      for (int mt = 0; mt < 4; mt++)
#pragma unroll
        for (int nt = 0; nt < 8; nt++)
          acc[mt][nt] = __builtin_amdgcn_mfma_f32_16x16x32_bf16(a[mt], b[nt], acc[mt][nt], 0, 0, 0);
    }
    if (more) {
      __syncthreads();          // all waves done reading As
      writeA();                 // overwrite A tile for step t+1 (residual A wait)
      __syncthreads();          // A visible + B(t+1) drained
    }
  }

  // C/D layout: col = lane&15, row = (lane>>4)*4 + q
#pragma unroll
  for (int mt = 0; mt < 4; mt++) {
#pragma unroll
    for (int q = 0; q < 4; q++) {
      int row = bm + wr * 64 + mt * 16 + lhi * 4 + q;
      if (row < M) {
#pragma unroll
        for (int nt = 0; nt < 8; nt++)
          C[(size_t)row * 256 + wc * 128 + nt * 16 + llo] = acc[mt][nt][q];
      }
    }
  }
}

// per-graph fused CSR build (layer 0 only): count -> scan -> fill, all in LDS.
__global__ __launch_bounds__(1024) void csr_graph_kernel(const int* __restrict__ src,
                                                         const int* __restrict__ dst,
                                                         int n,
                                                         int* __restrict__ deg,
                                                         int* __restrict__ offs,
                                                         int* __restrict__ eid) {
  __shared__ int sdeg[1024];
  __shared__ int soff[1024];
  __shared__ int scur[1024];
  __shared__ int spart[1024];
  const int g = blockIdx.x, tid = threadIdx.x;
  sdeg[tid] = 0;
  __syncthreads();
  const int e0 = g * EPG_;
  for (int e = tid; e < EPG_; e += 1024)
    atomicAdd(&sdeg[dst[e0 + e] - g * n], 1);
  __syncthreads();
  int v = (tid < n) ? sdeg[tid] : 0;
  spart[tid] = v;
  __syncthreads();
  for (int ofs = 1; ofs < 1024; ofs <<= 1) {
    int t = (tid >= ofs) ? spart[tid - ofs] : 0;
    __syncthreads();
    spart[tid] += t;
    __syncthreads();
  }
  if (tid < n) {
    soff[tid] = spart[tid] - sdeg[tid];   // exclusive prefix
    scur[tid] = 0;
    deg[g * n + tid] = sdeg[tid];
    offs[g * n + tid] = g * EPG_ + soff[tid];
  }
  __syncthreads();
  for (int e = tid; e < EPG_; e += 1024) {
    int ge = e0 + e;
    int d = dst[ge] - g * n;
    int p = atomicAdd(&scur[d], 1);
    eid[g * EPG_ + soff[d] + p] = src[ge];
  }
}

// fused: agg (CSR gather) -> mean -> +bl +Z -> relu -> X; T = x·wrel; R = x·wroot.
__global__ void agg_sage_dots_kernel(const float* __restrict__ Y,
                                     const int* __restrict__ eid, const int* __restrict__ offs,
                                     const int* __restrict__ deg,
                                     const float* __restrict__ bl,
                                     const float* __restrict__ wrel, const float* __restrict__ wroot,
                                     float* __restrict__ X, float* __restrict__ T,
                                     float* __restrict__ R, int M) {
  int wid = threadIdx.x >> 6, lane = threadIdx.x & 63;
  int i = blockIdx.x * 4 + wid;
  if (i >= M) return;
  int d = deg[i], o = offs[i];
  float a0 = 0.f, a1 = 0.f;
  for (int j = 0; j < d; j++) {
    int s = eid[o + j];
    a0 += Y[(size_t)s * 256 + lane];
    a1 += Y[(size_t)s * 256 + 64 + lane];
  }
  float ic = 1.f / fmaxf((float)d, 1.f);
  float v0 = a0 * ic + bl[lane] + Y[(size_t)i * 256 + 128 + lane];
  float v1 = a1 * ic + bl[64 + lane] + Y[(size_t)i * 256 + 192 + lane];
  v0 = fmaxf(v0, 0.f); v1 = fmaxf(v1, 0.f);
  X[(size_t)i * 128 + lane] = v0;
  X[(size_t)i * 128 + 64 + lane] = v1;
  float t = v0 * wrel[lane] + v1 * wrel[64 + lane];
  float r = v0 * wroot[lane] + v1 * wroot[64 + lane];
#pragma unroll
  for (int off = 32; off > 0; off >>= 1) {
    t += __shfl_down(t, off);
    r += __shfl_down(r, off);
  }
  if (lane == 0) { T[i] = t; R[i] = r; }
}

// fused per-graph tail: score via CSR -> O(n^2) rank top-k (exact lax.top_k order)
// -> gate/gather(NXB) -> f32 readout into H -> build NEXT-layer CSR in LDS.
template <int NP>
__global__ __launch_bounds__(1024) void pool_kernel(
    const float* __restrict__ X, const float* __restrict__ T, const float* __restrict__ R,
    const float* __restrict__ brel,
    const int* __restrict__ deg, const int* __restrict__ offs, const int* __restrict__ eid,
    int n, int k,
    unsigned short* __restrict__ NXB,
    int* __restrict__ degN, int* __restrict__ offsN, int* __restrict__ eidN,
    float* __restrict__ H) {
  __shared__ float val[NP];
  __shared__ int   ind[256];     // slot -> node (k <= 200)
  __shared__ int   lmap[NP];     // node -> slot or -1
  __shared__ float gate[256];
  __shared__ int   sdegN[256];
  __shared__ int   soffN[256];
  __shared__ float redmx[8][128];
  __shared__ float redsm[8][128];
  const int g = blockIdx.x, tid = threadIdx.x, nthr = blockDim.x;
  float b0 = brel[0];
  // scores
  for (int i = tid; i < n; i += nthr) {
    int gi = g * n + i;
    int dd = deg[gi], o = offs[gi];
    float s = 0.f;
    for (int j = 0; j < dd; j++) s += T[eid[o + j]];
    val[i] = s + R[gi] + b0;
    lmap[i] = -1;
  }
  __syncthreads();
  // rank selection: slot = #{j: val[j]>val[i] or (== and j<i)}; selected iff slot<k.
  for (int i = tid; i < n; i += nthr) {
    float vi = val[i];
    int rank = 0;
    for (int j = 0; j < n; j++) {
      float vj = val[j];
      rank += (vj > vi) || (vj == vi && j < i);
    }
    if (rank < k) {
      lmap[i] = rank;
      ind[rank] = i;
      gate[rank] = tanhf(vi);
    }
  }
  __syncthreads();
  // gather + gate -> NXB (bf16)
  for (int idx = tid; idx < k * 128; idx += nthr) {
    int t = idx >> 7, c = idx & 127;
    float v = X[(size_t)(g * n + ind[t]) * 128 + c] * gate[t];
    NXB[(size_t)(g * k + t) * 128 + c] = (unsigned short)f2bf1(v);
  }
  // readout in f32
  {
    int c = tid & 127, seg = tid >> 7;
    float mxv = -FLT_MAX, smv = 0.f;
    for (int t = seg; t < k; t += 8) {
      float v = X[(size_t)(g * n + ind[t]) * 128 + c] * gate[t];
      mxv = fmaxf(mxv, v);
      smv += v;
    }
    redmx[seg][c] = mxv;
    redsm[seg][c] = smv;
  }
  __syncthreads();
  if (tid < 128) {
    float Mv = redmx[0][tid], S = redsm[0][tid];
#pragma unroll
    for (int s2 = 1; s2 < 8; s2++) { Mv = fmaxf(Mv, redmx[s2][tid]); S += redsm[s2][tid]; }
    H[g * 256 + tid] += Mv;
    H[g * 256 + 128 + tid] += S / (float)k;
  }
  // build next-layer CSR (nodes g*k+slot; srcs remapped through lmap)
  if (degN) {
    for (int t = tid; t < k; t += nthr) sdegN[t] = 0;
    __syncthreads();
    for (int d = tid; d < n; d += nthr) {
      int ld = lmap[d];
      if (ld < 0) continue;
      int gd = g * n + d, dd = deg[gd], o = offs[gd];
      int cnt = 0;
      for (int j = 0; j < dd; j++)
        cnt += (lmap[eid[o + j] - g * n] >= 0);
      sdegN[ld] = cnt;            // unique slot per d — no atomic
    }
    __syncthreads();
    if (tid == 0) {
      int run = 0;
      for (int t = 0; t < k; t++) { soffN[t] = run; run += sdegN[t]; }
    }
    __syncthreads();
    for (int d = tid; d < n; d += nthr) {
      int ld = lmap[d];
      if (ld < 0) continue;
      int gd = g * n + d, dd = deg[gd], o = offs[gd];
      int p = 0;
      for (int j = 0; j < dd; j++) {
        int ls = lmap[eid[o + j] - g * n];
        if (ls >= 0) eidN[g * EPG_ + soffN[ld] + (p++)] = g * k + ls;
      }
      degN[g * k + ld] = p;
      offsN[g * k + ld] = g * EPG_ + soffN[ld];
    }
  }
}

__global__ void head_kernel(const float* __restrict__ H, const int* __restrict__ gpp,
                            const float* __restrict__ lin1_w, const float* __restrict__ lin1_b,
                            const float* __restrict__ lin2_w, const float* __restrict__ lin2_b,
                            const float* __restrict__ grade_w, const float* __restrict__ grade_b,
                            const float* __restrict__ haz_w, const float* __restrict__ haz_b,
                            float* __restrict__ out) {
  __shared__ float pooled[P_][256];
  __shared__ float h1[P_][NHID_];
  __shared__ float feats[P_][GDIM_];
  __shared__ int off[P_ + 1];
  int tid = threadIdx.x;
  if (tid == 0) {
    off[0] = 0;
    for (int p = 0; p < P_; p++) off[p + 1] = min(off[p] + gpp[p], G_);
  }
  __syncthreads();
  for (int idx = tid; idx < P_ * 256; idx += blockDim.x) {
    int p = idx >> 8, c = idx & 255;
    int a = off[p], b = (p == P_ - 1) ? G_ : off[p + 1];
    float s = 0.f;
    for (int gq = a; gq < b; gq++) s += H[gq * 256 + c];
    pooled[p][c] = s / (float)gpp[p];
  }
  __syncthreads();
  for (int idx = tid; idx < P_ * NHID_; idx += blockDim.x) {
    int p = idx >> 7, o = idx & 127;
    float acc = lin1_b[o];
    for (int c = 0; c < 256; c++) acc += pooled[p][c] * lin1_w[c * NHID_ + o];
    h1[p][o] = fmaxf(acc, 0.f);
  }
  __syncthreads();
  for (int idx = tid; idx < P_ * GDIM_; idx += blockDim.x) {
    int p = idx / GDIM_, o = idx % GDIM_;
    float acc = lin2_b[o];
    for (int c = 0; c < NHID_; c++) acc += h1[p][c] * lin2_w[c * GDIM_ + o];
    float f = fmaxf(acc, 0.f);
    feats[p][o] = f;
    out[p * GDIM_ + o] = f;
  }
  __syncthreads();
  if (tid < P_) {
    int p = tid;
    float l[3];
    float mx = -FLT_MAX;
    for (int j = 0; j < 3; j++) {
      float acc = grade_b[j];
      for (int c = 0; c < GDIM_; c++) acc += feats[p][c] * grade_w[c * 3 + j];
      l[j] = acc;
      mx = fmaxf(mx, acc);
    }
    float se = 0.f;
    for (int j = 0; j < 3; j++) se += expf(l[j] - mx);
    float lse = mx + logf(se);
    for (int j = 0; j < 3; j++) out[P_ * GDIM_ + p * 3 + j] = l[j] - lse;
    float z = haz_b[0];
    for (int c = 0; c < GDIM_; c++) z += feats[p][c] * haz_w[c];
    out[P_ * GDIM_ + P_ * 3 + p] = 6.f / (1.f + expf(-z)) - 3.f;
  }
}

// ---------------- launch ----------------
extern "C" void kernel_launch(void* const* d_in, const int* in_sizes, int n_in,
                              void* d_out, int out_size, void* d_ws, size_t ws_size,
                              hipStream_t stream) {
  (void)in_sizes; (void)n_in; (void)out_size; (void)ws_size;
  const float* x  = (const float*)d_in[0];
  const int* ei   = (const int*)d_in[1];
  const int* gpp  = (const int*)d_in[2];
  const float* c_wl[3]    = {(const float*)d_in[3],  (const float*)d_in[9],  (const float*)d_in[15]};
  const float* c_bl[3]    = {(const float*)d_in[4],  (const float*)d_in[10], (const float*)d_in[16]};
  const float* c_wr[3]    = {(const float*)d_in[5],  (const float*)d_in[11], (const float*)d_in[17]};
  const float* p_wrel[3]  = {(const float*)d_in[6],  (const float*)d_in[12], (const float*)d_in[18]};
  const float* p_brel[3]  = {(const float*)d_in[7],  (const float*)d_in[13], (const float*)d_in[19]};
  const float* p_wroot[3] = {(const float*)d_in[8],  (const float*)d_in[14], (const float*)d_in[20]};
  const float* lin1_w = (const float*)d_in[21];
  const float* lin1_b = (const float*)d_in[22];
  const float* lin2_w = (const float*)d_in[23];
  const float* lin2_b = (const float*)d_in[24];
  const float* grade_w = (const float*)d_in[25];
  const float* grade_b = (const float*)d_in[26];
  const float* haz_w = (const float*)d_in[27];
  const float* haz_b = (const float*)d_in[28];

  char* wsb = (char*)d_ws;
  size_t off = 0;
  auto alloc = [&](size_t bytes) -> void* {
    void* p = wsb + off;
    off += (bytes + 255) & ~(size_t)255;
    return p;
  };
  int*            SCALE = (int*)alloc(64 * 4);
  unsigned short* WT0   = (unsigned short*)alloc((size_t)256 * KPAD_ * 2);
  unsigned short* WT1   = (unsigned short*)alloc((size_t)256 * 128 * 2);
  unsigned short* WT2   = (unsigned short*)alloc((size_t)256 * 128 * 2);
  float*          YZ    = (float*)alloc((size_t)M0_ * 256 * 4);
  float*          H     = (float*)alloc((size_t)G_ * 256 * 4);
  float* X     = (float*)alloc((size_t)M0_ * 128 * 4);
  unsigned short* NXB = (unsigned short*)alloc((size_t)MPAD1_ * 128 * 2);
  float* T     = (float*)alloc((size_t)M0_ * 4);
  float* R     = (float*)alloc((size_t)M0_ * 4);
  int*   DEG0  = (int*)alloc((size_t)M0_ * 4);
  int*   OFF0  = (int*)alloc((size_t)M0_ * 4);
  int*   EID0  = (int*)alloc((size_t)NEDGE * 4);
  int*   DEG1  = (int*)alloc((size_t)M1_ * 4);
  int*   OFF1  = (int*)alloc((size_t)M1_ * 4);
  int*   EID1  = (int*)alloc((size_t)NEDGE * 4);

  const int* src0 = ei;
  const int* dst0 = ei + NEDGE;

  hipMemsetAsync(H, 0, G_ * 256 * sizeof(float), stream);
  hipMemsetAsync(SCALE, 0, 12 * sizeof(int), stream);

  // ---- setup ----
  colmax_kernel<<<128, 256, 0, stream>>>(x, SCALE);
  build_wt0_kernel<<<(256 * KPAD_ + 255) / 256, 256, 0, stream>>>(c_wl[0], c_wr[0], SCALE, WT0);
  build_wt12_kernel<<<(2 * 256 * 128 + 255) / 256, 256, 0, stream>>>(c_wl[1], c_wr[1], c_wl[2], c_wr[2], WT1, WT2);

  // ---- layer 0 ----
  csr_graph_kernel<<<G_, 1024, 0, stream>>>(src0, dst0, N0_, DEG0, OFF0, EID0);
  mfma_gemm_kernel<true><<<MPAD0_ / 128, 256, 0, stream>>>(x, nullptr, WT0, YZ, M0_, FEAT_, KPAD_, FEAT_, KPAD_ / 64);
  agg_sage_dots_kernel<<<(M0_ + 3) / 4, 256, 0, stream>>>(YZ, EID0, OFF0, DEG0, c_bl[0], p_wrel[0], p_wroot[0], X, T, R, M0_);
  pool_kernel<1024><<<G_, 1024, 0, stream>>>(X, T, R, p_brel[0], DEG0, OFF0, EID0,
                                             N0_, K0_, NXB, DEG1, OFF1, EID1, H);

  // ---- layer 1 ----
  mfma_gemm_kernel<false><<<MPAD1_ / 128, 256, 0, stream>>>(nullptr, NXB, WT1, YZ, M1_, 128, 128, 128, 2);
  agg_sage_dots_kernel<<<(M1_ + 3) / 4, 256, 0, stream>>>(YZ, EID1, OFF1, DEG1, c_bl[1], p_wrel[1], p_wroot[1], X, T, R, M1_);
  pool_kernel<256><<<G_, 1024, 0, stream>>>(X, T, R, p_brel[1], DEG1, OFF1, EID1,
                                            K0_, K1_, NXB, DEG0, OFF0, EID0, H);

  // ---- layer 2 ----
  mfma_gemm_kernel<false><<<MPAD2_ / 128, 256, 0, stream>>>(nullptr, NXB, WT2, YZ, M2_, 128, 128, 128, 2);
  agg_sage_dots_kernel<<<(M2_ + 3) / 4, 256, 0, stream>>>(YZ, EID0, OFF0, DEG0, c_bl[2], p_wrel[2], p_wroot[2], X, T, R, M2_);
  pool_kernel<64><<<G_, 1024, 0, stream>>>(X, T, R, p_brel[2], DEG0, OFF0, EID0,
                                           K1_, K2_, NXB, nullptr, nullptr, nullptr, H);

  // ---- head ----
  head_kernel<<<1, 256, 0, stream>>>(H, gpp, lin1_w, lin1_b, lin2_w, lin2_b,
                                     grade_w, grade_b, haz_w, haz_b, (float*)d_out);
}

// Round 13
// 285.239 us; speedup vs baseline: 1.1754x; 1.1754x over previous
//
#include <hip/hip_runtime.h>
#include <math.h>
#include <cfloat>

// ---------------- problem constants ----------------
#define G_    50
#define N0_   1000
#define NEDGE 200000
#define EPG_  (NEDGE/G_)   // 4000 edges per graph (contiguous slots)
#define P_    10
#define FEAT_ 1036
#define NHID_ 128
#define GDIM_ 32
#define K0_   200
#define K1_   40
#define K2_   8
#define M0_   (G_*N0_)     // 50000
#define M1_   (G_*K0_)     // 10000
#define M2_   (G_*K1_)     // 2000

#define KPAD_ 1088         // 1036 padded to multiple of 64
#define MPAD0_ 50048       // mult of 128
#define MPAD1_ 10112       // mult of 128
#define MPAD2_ 2048        // mult of 128

typedef __attribute__((ext_vector_type(8))) short s16x8;
typedef __attribute__((ext_vector_type(4))) float f32x4;

__device__ __forceinline__ unsigned f2bf1(float f) {   // bf16 bits, RNE
  unsigned u = __float_as_uint(f);
  return (u + 0x7FFFu + ((u >> 16) & 1u)) >> 16;
}
__device__ __forceinline__ unsigned packbf(float a, float b) {
  return f2bf1(a) | (f2bf1(b) << 16);
}

__device__ __forceinline__ void gload_lds16(const void* g, void* l) {
  __builtin_amdgcn_global_load_lds((const __attribute__((address_space(1))) void*)g,
                                   (__attribute__((address_space(3))) void*)l, 16, 0, 0);
}

// ---------------- kernels ----------------

// row-major colmax
__global__ void colmax_kernel(const float* __restrict__ x, int* __restrict__ scale_i) {
  int tid = threadIdx.x, wave = tid >> 6, lane = tid & 63;
  float mx[12];
#pragma unroll
  for (int j = 0; j < 12; j++) mx[j] = 0.f;
  for (int r = blockIdx.x * 256 + tid; r < M0_; r += gridDim.x * 256) {
    const float4* p = (const float4*)(x + (size_t)r * FEAT_);
    float4 a = p[0], b = p[1], c = p[2];
    mx[0] = fmaxf(mx[0], a.x); mx[1] = fmaxf(mx[1], a.y);
    mx[2] = fmaxf(mx[2], a.z); mx[3] = fmaxf(mx[3], a.w);
    mx[4] = fmaxf(mx[4], b.x); mx[5] = fmaxf(mx[5], b.y);
    mx[6] = fmaxf(mx[6], b.z); mx[7] = fmaxf(mx[7], b.w);
    mx[8] = fmaxf(mx[8], c.x); mx[9] = fmaxf(mx[9], c.y);
    mx[10] = fmaxf(mx[10], c.z); mx[11] = fmaxf(mx[11], c.w);
  }
#pragma unroll
  for (int off = 32; off > 0; off >>= 1)
#pragma unroll
    for (int j = 0; j < 12; j++) mx[j] = fmaxf(mx[j], __shfl_down(mx[j], off));
  __shared__ float red[4][12];
  if (lane == 0)
#pragma unroll
    for (int j = 0; j < 12; j++) red[wave][j] = mx[j];
  __syncthreads();
  if (tid < 12) {
    float m = fmaxf(fmaxf(red[0][tid], red[1][tid]), fmaxf(red[2][tid], red[3][tid]));
    atomicMax(scale_i + tid, __float_as_int(m));
  }
}

__global__ void build_wt0_kernel(const float* __restrict__ wl, const float* __restrict__ wr,
                                 const int* __restrict__ scale_i, unsigned short* __restrict__ WT) {
  int idx = blockIdx.x * blockDim.x + threadIdx.x;
  if (idx >= 256 * KPAD_) return;
  int c = idx / KPAD_, j = idx % KPAD_;
  float w = 0.f;
  if (j < FEAT_) {
    w = (c < NHID_) ? wl[j * NHID_ + c] : wr[j * NHID_ + (c - NHID_)];
    if (j < 12) w *= 1.0f / __int_as_float(scale_i[j]);
  }
  WT[idx] = (unsigned short)f2bf1(w);
}

__global__ void build_wt12_kernel(const float* __restrict__ wl1, const float* __restrict__ wr1,
                                  const float* __restrict__ wl2, const float* __restrict__ wr2,
                                  unsigned short* __restrict__ WTA, unsigned short* __restrict__ WTB) {
  int idx = blockIdx.x * blockDim.x + threadIdx.x;
  if (idx >= 2 * 256 * 128) return;
  int l = idx >> 15, r = idx & 32767;
  int c = r >> 7, j = r & 127;
  const float* wl = l ? wl2 : wl1;
  const float* wr = l ? wr2 : wr1;
  float w = (c < NHID_) ? wl[j * NHID_ + c] : wr[j * NHID_ + (c - NHID_)];
  (l ? WTB : WTA)[r] = (unsigned short)f2bf1(w);
}

// C[M x 256] = A @ WT^T.  128x256 tile (full N); 4 waves 2x2, each 64x128.
// BK=64 stored as two 32-wide panels. A reg-staged f32->bf16 (or bf16 copy);
// B via global_load_lds.  [r9 config — best measured]
template <bool AF32>
__global__ __launch_bounds__(256) void mfma_gemm_kernel(const float* __restrict__ Af,
                                                        const unsigned short* __restrict__ Ab,
                                                        const unsigned short* __restrict__ WT,
                                                        float* __restrict__ C, int M,
                                                        int lda, int ldb, int kvalid, int ksteps) {
  __shared__ unsigned short As[2 * 128 * 32];   // panel kk at + kk*4096
  __shared__ unsigned short Bs[2 * 256 * 32];   // panel kk at + kk*8192
  const int bm = blockIdx.x * 128;
  const int tid = threadIdx.x, wave = tid >> 6, lane = tid & 63;
  const int wr = wave >> 1, wc = wave & 1;
  const int lhi = lane >> 4, llo = lane & 15;
  const int arow = tid >> 1, ahalf = tid & 1;   // ahalf = k-panel; 32 k-elems/thread
  f32x4 acc[4][8] = {};

  for (int st = 0; st < ksteps; st++) {
    const int k0 = st * 64;
    // ---- stage B: 256 cols x 64 k bf16 = 2048 chunks of 16B, 8 per thread
#pragma unroll
    for (int it = 0; it < 8; it++) {
      int c = it * 256 + wave * 64 + lane;         // 0..2047, LDS-linear
      int kk = c >> 10, r = (c >> 2) & 255, cb = c & 3;
      gload_lds16(WT + (size_t)r * ldb + k0 + kk * 32 + cb * 8, Bs + (size_t)c * 8);
    }
    // ---- stage A: row=arow, panel=ahalf, k in [k0+ahalf*32, +32)
    {
      int gr = bm + arow;
      int gk = k0 + ahalf * 32;
      unsigned short* dstp = As + ahalf * 4096 + arow * 32;
      if (AF32) {
        float f[32];
        if (gr < M && gk + 32 <= kvalid) {
          const float4* ap = (const float4*)(Af + (size_t)gr * lda + gk);
#pragma unroll
          for (int j = 0; j < 8; j++) {
            float4 v = ap[j];
            f[4 * j] = v.x; f[4 * j + 1] = v.y; f[4 * j + 2] = v.z; f[4 * j + 3] = v.w;
          }
        } else {
          const float* ap = Af + (size_t)gr * lda + gk;
#pragma unroll
          for (int j = 0; j < 32; j++)
            f[j] = (gr < M && gk + j < kvalid) ? ap[j] : 0.f;
        }
#pragma unroll
        for (int j = 0; j < 4; j++) {
          uint4 p;
          p.x = packbf(f[8 * j + 0], f[8 * j + 1]); p.y = packbf(f[8 * j + 2], f[8 * j + 3]);
          p.z = packbf(f[8 * j + 4], f[8 * j + 5]); p.w = packbf(f[8 * j + 6], f[8 * j + 7]);
          *(uint4*)(dstp + j * 8) = p;
        }
      } else {
        const uint4* ap = (const uint4*)(Ab + (size_t)gr * lda + gk);
#pragma unroll
        for (int j = 0; j < 4; j++) ((uint4*)dstp)[j] = ap[j];
      }
    }
    __syncthreads();   // drain vmcnt (gload_lds) + lgkmcnt (ds_write)

#pragma unroll
    for (int kk = 0; kk < 2; kk++) {
      s16x8 a[4], b[8];
#pragma unroll
      for (int mt = 0; mt < 4; mt++)
        a[mt] = *(const s16x8*)&As[kk * 4096 + (wr * 64 + mt * 16 + llo) * 32 + lhi * 8];
#pragma unroll
      for (int nt = 0; nt < 8; nt++)
        b[nt] = *(const s16x8*)&Bs[kk * 8192 + (wc * 128 + nt * 16 + llo) * 32 + lhi * 8];
#pragma unroll
      for (int mt = 0; mt < 4; mt++)
#pragma unroll
        for (int nt = 0; nt < 8; nt++)
          acc[mt][nt] = __builtin_amdgcn_mfma_f32_16x16x32_bf16(a[mt], b[nt], acc[mt][nt], 0, 0, 0);
    }
    __syncthreads();
  }

  // C/D layout: col = lane&15, row = (lane>>4)*4 + q
#pragma unroll
  for (int mt = 0; mt < 4; mt++) {
#pragma unroll
    for (int q = 0; q < 4; q++) {
      int row = bm + wr * 64 + mt * 16 + lhi * 4 + q;
      if (row < M) {
#pragma unroll
        for (int nt = 0; nt < 8; nt++)
          C[(size_t)row * 256 + wc * 128 + nt * 16 + llo] = acc[mt][nt][q];
      }
    }
  }
}

// per-graph fused CSR build: count -> scan -> fill, all in LDS. One block/graph.
__global__ __launch_bounds__(1024) void csr_graph_kernel(const int* __restrict__ src,
                                                         const int* __restrict__ dst,
                                                         const float* __restrict__ m, int n,
                                                         int* __restrict__ deg,
                                                         int* __restrict__ offs,
                                                         int* __restrict__ eid) {
  __shared__ int sdeg[1024];
  __shared__ int soff[1024];
  __shared__ int scur[1024];
  __shared__ int spart[1024];
  const int g = blockIdx.x, tid = threadIdx.x;
  sdeg[tid] = 0;
  __syncthreads();
  const int e0 = g * EPG_;
  for (int e = tid; e < EPG_; e += 1024) {
    int ge = e0 + e;
    if (!m || m[ge] != 0.f) atomicAdd(&sdeg[dst[ge] - g * n], 1);
  }
  __syncthreads();
  int v = (tid < n) ? sdeg[tid] : 0;
  spart[tid] = v;
  __syncthreads();
  for (int ofs = 1; ofs < 1024; ofs <<= 1) {
    int t = (tid >= ofs) ? spart[tid - ofs] : 0;
    __syncthreads();
    spart[tid] += t;
    __syncthreads();
  }
  if (tid < n) {
    soff[tid] = spart[tid] - sdeg[tid];   // exclusive prefix
    scur[tid] = 0;
    deg[g * n + tid] = sdeg[tid];
    offs[g * n + tid] = g * EPG_ + soff[tid];
  }
  __syncthreads();
  for (int e = tid; e < EPG_; e += 1024) {
    int ge = e0 + e;
    if (!m || m[ge] != 0.f) {
      int d = dst[ge] - g * n;
      int p = atomicAdd(&scur[d], 1);
      eid[g * EPG_ + soff[d] + p] = src[ge];
    }
  }
}

// fused: agg (CSR gather) -> mean -> +bl +Z -> relu -> X; T = x·wrel; R = x·wroot.
__global__ void agg_sage_dots_kernel(const float* __restrict__ Y,
                                     const int* __restrict__ eid, const int* __restrict__ offs,
                                     const int* __restrict__ deg,
                                     const float* __restrict__ bl,
                                     const float* __restrict__ wrel, const float* __restrict__ wroot,
                                     float* __restrict__ X, float* __restrict__ T,
                                     float* __restrict__ R, int M) {
  int wid = threadIdx.x >> 6, lane = threadIdx.x & 63;
  int i = blockIdx.x * 4 + wid;
  if (i >= M) return;
  int d = deg[i], o = offs[i];
  float a0 = 0.f, a1 = 0.f;
  for (int j = 0; j < d; j++) {
    int s = eid[o + j];
    a0 += Y[(size_t)s * 256 + lane];
    a1 += Y[(size_t)s * 256 + 64 + lane];
  }
  float ic = 1.f / fmaxf((float)d, 1.f);
  float v0 = a0 * ic + bl[lane] + Y[(size_t)i * 256 + 128 + lane];
  float v1 = a1 * ic + bl[64 + lane] + Y[(size_t)i * 256 + 192 + lane];
  v0 = fmaxf(v0, 0.f); v1 = fmaxf(v1, 0.f);
  X[(size_t)i * 128 + lane] = v0;
  X[(size_t)i * 128 + 64 + lane] = v1;
  float t = v0 * wrel[lane] + v1 * wrel[64 + lane];
  float r = v0 * wroot[lane] + v1 * wroot[64 + lane];
#pragma unroll
  for (int off = 32; off > 0; off >>= 1) {
    t += __shfl_down(t, off);
    r += __shfl_down(r, off);
  }
  if (lane == 0) { T[i] = t; R[i] = r; }
}

// fused per-graph tail: score via CSR -> bitonic top-k -> gate/gather(NXB)
// -> f32 readout into H -> edge remap. One 1024-thread block per graph.
template <int NP>
__global__ __launch_bounds__(1024) void pool_kernel(
    const float* __restrict__ X, const float* __restrict__ T, const float* __restrict__ R,
    const float* __restrict__ brel,
    const int* __restrict__ src, const int* __restrict__ dst, const float* __restrict__ m,
    const int* __restrict__ deg, const int* __restrict__ offs, const int* __restrict__ eid,
    int n, int k,
    unsigned short* __restrict__ NXB,
    int* __restrict__ nsrc, int* __restrict__ ndst, float* __restrict__ nm,
    float* __restrict__ H) {
  __shared__ float val[NP];
  __shared__ int   ind[NP];
  __shared__ int   lmap[NP];
  __shared__ float gate[256];
  __shared__ float redmx[8][128];
  __shared__ float redsm[8][128];
  const int g = blockIdx.x, tid = threadIdx.x, nthr = blockDim.x;
  float b0 = brel[0];
  for (int i = tid; i < NP; i += nthr) {
    lmap[i] = -1;
    float v = -FLT_MAX;
    if (i < n) {
      int gi = g * n + i;
      int dd = deg[gi], o = offs[gi];
      float s = 0.f;
      for (int j = 0; j < dd; j++) s += T[eid[o + j]];
      v = s + R[gi] + b0;
    }
    val[i] = v;
    ind[i] = i;
  }
  __syncthreads();
  for (int kk = 2; kk <= NP; kk <<= 1) {
    for (int j = kk >> 1; j > 0; j >>= 1) {
      for (int i = tid; i < NP; i += nthr) {
        int ixj = i ^ j;
        if (ixj > i) {
          bool desc = ((i & kk) == 0);
          float vi = val[i], vj = val[ixj];
          if (desc ? (vi < vj) : (vi > vj)) {
            val[i] = vj; val[ixj] = vi;
            int tmp = ind[i]; ind[i] = ind[ixj]; ind[ixj] = tmp;
          }
        }
      }
      __syncthreads();
    }
  }
  for (int t = tid; t < k; t += nthr) {
    lmap[ind[t]] = t;
    gate[t] = tanhf(val[t]);
  }
  __syncthreads();
  for (int idx = tid; idx < k * 128; idx += nthr) {
    int t = idx >> 7, c = idx & 127;
    float v = X[(size_t)(g * n + ind[t]) * 128 + c] * gate[t];
    NXB[(size_t)(g * k + t) * 128 + c] = (unsigned short)f2bf1(v);
  }
  {
    int c = tid & 127, seg = tid >> 7;
    float mxv = -FLT_MAX, smv = 0.f;
    for (int t = seg; t < k; t += 8) {
      float v = X[(size_t)(g * n + ind[t]) * 128 + c] * gate[t];
      mxv = fmaxf(mxv, v);
      smv += v;
    }
    redmx[seg][c] = mxv;
    redsm[seg][c] = smv;
  }
  __syncthreads();
  if (tid < 128) {
    float Mv = redmx[0][tid], S = redsm[0][tid];
#pragma unroll
    for (int s2 = 1; s2 < 8; s2++) { Mv = fmaxf(Mv, redmx[s2][tid]); S += redsm[s2][tid]; }
    H[g * 256 + tid] += Mv;
    H[g * 256 + 128 + tid] += S / (float)k;
  }
  if (nsrc) {
    const int e0 = g * EPG_;
    for (int e = tid; e < EPG_; e += nthr) {
      int ge = e0 + e;
      int ls = lmap[src[ge] - g * n], ld = lmap[dst[ge] - g * n];
      float me = m ? m[ge] : 1.f;
      nm[ge] = (ls >= 0 && ld >= 0) ? me : 0.f;
      nsrc[ge] = g * k + max(ls, 0);
      ndst[ge] = g * k + max(ld, 0);
    }
  }
}

__global__ void head_kernel(const float* __restrict__ H, const int* __restrict__ gpp,
                            const float* __restrict__ lin1_w, const float* __restrict__ lin1_b,
                            const float* __restrict__ lin2_w, const float* __restrict__ lin2_b,
                            const float* __restrict__ grade_w, const float* __restrict__ grade_b,
                            const float* __restrict__ haz_w, const float* __restrict__ haz_b,
                            float* __restrict__ out) {
  __shared__ float pooled[P_][256];
  __shared__ float h1[P_][NHID_];
  __shared__ float feats[P_][GDIM_];
  __shared__ int off[P_ + 1];
  int tid = threadIdx.x;
  if (tid == 0) {
    off[0] = 0;
    for (int p = 0; p < P_; p++) off[p + 1] = min(off[p] + gpp[p], G_);
  }
  __syncthreads();
  for (int idx = tid; idx < P_ * 256; idx += blockDim.x) {
    int p = idx >> 8, c = idx & 255;
    int a = off[p], b = (p == P_ - 1) ? G_ : off[p + 1];
    float s = 0.f;
    for (int gq = a; gq < b; gq++) s += H[gq * 256 + c];
    pooled[p][c] = s / (float)gpp[p];
  }
  __syncthreads();
  for (int idx = tid; idx < P_ * NHID_; idx += blockDim.x) {
    int p = idx >> 7, o = idx & 127;
    float acc = lin1_b[o];
    for (int c = 0; c < 256; c++) acc += pooled[p][c] * lin1_w[c * NHID_ + o];
    h1[p][o] = fmaxf(acc, 0.f);
  }
  __syncthreads();
  for (int idx = tid; idx < P_ * GDIM_; idx += blockDim.x) {
    int p = idx / GDIM_, o = idx % GDIM_;
    float acc = lin2_b[o];
    for (int c = 0; c < NHID_; c++) acc += h1[p][c] * lin2_w[c * GDIM_ + o];
    float f = fmaxf(acc, 0.f);
    feats[p][o] = f;
    out[p * GDIM_ + o] = f;
  }
  __syncthreads();
  if (tid < P_) {
    int p = tid;
    float l[3];
    float mx = -FLT_MAX;
    for (int j = 0; j < 3; j++) {
      float acc = grade_b[j];
      for (int c = 0; c < GDIM_; c++) acc += feats[p][c] * grade_w[c * 3 + j];
      l[j] = acc;
      mx = fmaxf(mx, acc);
    }
    float se = 0.f;
    for (int j = 0; j < 3; j++) se += expf(l[j] - mx);
    float lse = mx + logf(se);
    for (int j = 0; j < 3; j++) out[P_ * GDIM_ + p * 3 + j] = l[j] - lse;
    float z = haz_b[0];
    for (int c = 0; c < GDIM_; c++) z += feats[p][c] * haz_w[c];
    out[P_ * GDIM_ + P_ * 3 + p] = 6.f / (1.f + expf(-z)) - 3.f;
  }
}

// ---------------- launch ----------------
extern "C" void kernel_launch(void* const* d_in, const int* in_sizes, int n_in,
                              void* d_out, int out_size, void* d_ws, size_t ws_size,
                              hipStream_t stream) {
  (void)in_sizes; (void)n_in; (void)out_size; (void)ws_size;
  const float* x  = (const float*)d_in[0];
  const int* ei   = (const int*)d_in[1];
  const int* gpp  = (const int*)d_in[2];
  const float* c_wl[3]    = {(const float*)d_in[3],  (const float*)d_in[9],  (const float*)d_in[15]};
  const float* c_bl[3]    = {(const float*)d_in[4],  (const float*)d_in[10], (const float*)d_in[16]};
  const float* c_wr[3]    = {(const float*)d_in[5],  (const float*)d_in[11], (const float*)d_in[17]};
  const float* p_wrel[3]  = {(const float*)d_in[6],  (const float*)d_in[12], (const float*)d_in[18]};
  const float* p_brel[3]  = {(const float*)d_in[7],  (const float*)d_in[13], (const float*)d_in[19]};
  const float* p_wroot[3] = {(const float*)d_in[8],  (const float*)d_in[14], (const float*)d_in[20]};
  const float* lin1_w = (const float*)d_in[21];
  const float* lin1_b = (const float*)d_in[22];
  const float* lin2_w = (const float*)d_in[23];
  const float* lin2_b = (const float*)d_in[24];
  const float* grade_w = (const float*)d_in[25];
  const float* grade_b = (const float*)d_in[26];
  const float* haz_w = (const float*)d_in[27];
  const float* haz_b = (const float*)d_in[28];

  char* wsb = (char*)d_ws;
  size_t off = 0;
  auto alloc = [&](size_t bytes) -> void* {
    void* p = wsb + off;
    off += (bytes + 255) & ~(size_t)255;
    return p;
  };
  int*            SCALE = (int*)alloc(64 * 4);
  unsigned short* WT0   = (unsigned short*)alloc((size_t)256 * KPAD_ * 2);
  unsigned short* WT1   = (unsigned short*)alloc((size_t)256 * 128 * 2);
  unsigned short* WT2   = (unsigned short*)alloc((size_t)256 * 128 * 2);
  float*          YZ    = (float*)alloc((size_t)M0_ * 256 * 4);
  float*          H     = (float*)alloc((size_t)G_ * 256 * 4);
  float* X     = (float*)alloc((size_t)M0_ * 128 * 4);
  unsigned short* NXB = (unsigned short*)alloc((size_t)MPAD1_ * 128 * 2);
  float* T     = (float*)alloc((size_t)M0_ * 4);
  float* R     = (float*)alloc((size_t)M0_ * 4);
  int*   DEG   = (int*)alloc((size_t)M0_ * 4);
  int*   OFF   = (int*)alloc((size_t)M0_ * 4);
  int*   EID   = (int*)alloc((size_t)NEDGE * 4);
  int*   E1S   = (int*)alloc((size_t)NEDGE * 4);
  int*   E1D   = (int*)alloc((size_t)NEDGE * 4);
  float* E1M   = (float*)alloc((size_t)NEDGE * 4);
  int*   E2S   = (int*)alloc((size_t)NEDGE * 4);
  int*   E2D   = (int*)alloc((size_t)NEDGE * 4);
  float* E2M   = (float*)alloc((size_t)NEDGE * 4);

  const int* src0 = ei;
  const int* dst0 = ei + NEDGE;

  hipMemsetAsync(H, 0, G_ * 256 * sizeof(float), stream);
  hipMemsetAsync(SCALE, 0, 12 * sizeof(int), stream);

  // ---- setup ----
  colmax_kernel<<<128, 256, 0, stream>>>(x, SCALE);
  build_wt0_kernel<<<(256 * KPAD_ + 255) / 256, 256, 0, stream>>>(c_wl[0], c_wr[0], SCALE, WT0);
  build_wt12_kernel<<<(2 * 256 * 128 + 255) / 256, 256, 0, stream>>>(c_wl[1], c_wr[1], c_wl[2], c_wr[2], WT1, WT2);

  // ---- layer 0 ----
  csr_graph_kernel<<<G_, 1024, 0, stream>>>(src0, dst0, nullptr, N0_, DEG, OFF, EID);
  mfma_gemm_kernel<true><<<MPAD0_ / 128, 256, 0, stream>>>(x, nullptr, WT0, YZ, M0_, FEAT_, KPAD_, FEAT_, KPAD_ / 64);
  agg_sage_dots_kernel<<<(M0_ + 3) / 4, 256, 0, stream>>>(YZ, EID, OFF, DEG, c_bl[0], p_wrel[0], p_wroot[0], X, T, R, M0_);
  pool_kernel<1024><<<G_, 1024, 0, stream>>>(X, T, R, p_brel[0], src0, dst0, nullptr,
                                             DEG, OFF, EID, N0_, K0_, NXB, E1S, E1D, E1M, H);

  // ---- layer 1 ----
  csr_graph_kernel<<<G_, 1024, 0, stream>>>(E1S, E1D, E1M, K0_, DEG, OFF, EID);
  mfma_gemm_kernel<false><<<MPAD1_ / 128, 256, 0, stream>>>(nullptr, NXB, WT1, YZ, M1_, 128, 128, 128, 2);
  agg_sage_dots_kernel<<<(M1_ + 3) / 4, 256, 0, stream>>>(YZ, EID, OFF, DEG, c_bl[1], p_wrel[1], p_wroot[1], X, T, R, M1_);
  pool_kernel<256><<<G_, 1024, 0, stream>>>(X, T, R, p_brel[1], E1S, E1D, E1M,
                                            DEG, OFF, EID, K0_, K1_, NXB, E2S, E2D, E2M, H);

  // ---- layer 2 ----
  csr_graph_kernel<<<G_, 1024, 0, stream>>>(E2S, E2D, E2M, K1_, DEG, OFF, EID);
  mfma_gemm_kernel<false><<<MPAD2_ / 128, 256, 0, stream>>>(nullptr, NXB, WT2, YZ, M2_, 128, 128, 128, 2);
  agg_sage_dots_kernel<<<(M2_ + 3) / 4, 256, 0, stream>>>(YZ, EID, OFF, DEG, c_bl[2], p_wrel[2], p_wroot[2], X, T, R, M2_);
  pool_kernel<64><<<G_, 1024, 0, stream>>>(X, T, R, p_brel[2], E2S, E2D, E2M,
                                           DEG, OFF, EID, K1_, K2_, NXB, nullptr, nullptr, nullptr, H);

  // ---- head ----
  head_kernel<<<1, 256, 0, stream>>>(H, gpp, lin1_w, lin1_b, lin2_w, lin2_b,
                                     grade_w, grade_b, haz_w, haz_b, (float*)d_out);
}

// Round 14
// 272.941 us; speedup vs baseline: 1.2283x; 1.0451x over previous
//
#include <hip/hip_runtime.h>
#include <math.h>
#include <cfloat>

// ---------------- problem constants ----------------
#define G_    50
#define N0_   1000
#define NEDGE 200000
#define EPG_  (NEDGE/G_)   // 4000 edges per graph (contiguous slots)
#define P_    10
#define FEAT_ 1036
#define NHID_ 128
#define GDIM_ 32
#define K0_   200
#define K1_   40
#define K2_   8
#define M0_   (G_*N0_)     // 50000
#define M1_   (G_*K0_)     // 10000
#define M2_   (G_*K1_)     // 2000

#define KPAD_ 1088         // 1036 padded to multiple of 64
#define MPAD0_ 50048       // mult of 128
#define MPAD1_ 10112       // mult of 128
#define MPAD2_ 2048        // mult of 128

typedef __attribute__((ext_vector_type(8))) short s16x8;
typedef __attribute__((ext_vector_type(4))) float f32x4;

__device__ __forceinline__ unsigned f2bf1(float f) {   // bf16 bits, RNE
  unsigned u = __float_as_uint(f);
  return (u + 0x7FFFu + ((u >> 16) & 1u)) >> 16;
}
__device__ __forceinline__ unsigned packbf(float a, float b) {
  return f2bf1(a) | (f2bf1(b) << 16);
}

__device__ __forceinline__ void gload_lds16(const void* g, void* l) {
  __builtin_amdgcn_global_load_lds((const __attribute__((address_space(1))) void*)g,
                                   (__attribute__((address_space(3))) void*)l, 16, 0, 0);
}

// ---------------- kernels ----------------

// row-major colmax
__global__ void colmax_kernel(const float* __restrict__ x, int* __restrict__ scale_i) {
  int tid = threadIdx.x, wave = tid >> 6, lane = tid & 63;
  float mx[12];
#pragma unroll
  for (int j = 0; j < 12; j++) mx[j] = 0.f;
  for (int r = blockIdx.x * 256 + tid; r < M0_; r += gridDim.x * 256) {
    const float4* p = (const float4*)(x + (size_t)r * FEAT_);
    float4 a = p[0], b = p[1], c = p[2];
    mx[0] = fmaxf(mx[0], a.x); mx[1] = fmaxf(mx[1], a.y);
    mx[2] = fmaxf(mx[2], a.z); mx[3] = fmaxf(mx[3], a.w);
    mx[4] = fmaxf(mx[4], b.x); mx[5] = fmaxf(mx[5], b.y);
    mx[6] = fmaxf(mx[6], b.z); mx[7] = fmaxf(mx[7], b.w);
    mx[8] = fmaxf(mx[8], c.x); mx[9] = fmaxf(mx[9], c.y);
    mx[10] = fmaxf(mx[10], c.z); mx[11] = fmaxf(mx[11], c.w);
  }
#pragma unroll
  for (int off = 32; off > 0; off >>= 1)
#pragma unroll
    for (int j = 0; j < 12; j++) mx[j] = fmaxf(mx[j], __shfl_down(mx[j], off));
  __shared__ float red[4][12];
  if (lane == 0)
#pragma unroll
    for (int j = 0; j < 12; j++) red[wave][j] = mx[j];
  __syncthreads();
  if (tid < 12) {
    float m = fmaxf(fmaxf(red[0][tid], red[1][tid]), fmaxf(red[2][tid], red[3][tid]));
    atomicMax(scale_i + tid, __float_as_int(m));
  }
}

__global__ void build_wt0_kernel(const float* __restrict__ wl, const float* __restrict__ wr,
                                 const int* __restrict__ scale_i, unsigned short* __restrict__ WT) {
  int idx = blockIdx.x * blockDim.x + threadIdx.x;
  if (idx >= 256 * KPAD_) return;
  int c = idx / KPAD_, j = idx % KPAD_;
  float w = 0.f;
  if (j < FEAT_) {
    w = (c < NHID_) ? wl[j * NHID_ + c] : wr[j * NHID_ + (c - NHID_)];
    if (j < 12) w *= 1.0f / __int_as_float(scale_i[j]);
  }
  WT[idx] = (unsigned short)f2bf1(w);
}

__global__ void build_wt12_kernel(const float* __restrict__ wl1, const float* __restrict__ wr1,
                                  const float* __restrict__ wl2, const float* __restrict__ wr2,
                                  unsigned short* __restrict__ WTA, unsigned short* __restrict__ WTB) {
  int idx = blockIdx.x * blockDim.x + threadIdx.x;
  if (idx >= 2 * 256 * 128) return;
  int l = idx >> 15, r = idx & 32767;
  int c = r >> 7, j = r & 127;
  const float* wl = l ? wl2 : wl1;
  const float* wr = l ? wr2 : wr1;
  float w = (c < NHID_) ? wl[j * NHID_ + c] : wr[j * NHID_ + (c - NHID_)];
  (l ? WTB : WTA)[r] = (unsigned short)f2bf1(w);
}

// C[M x 256] = A @ WT^T.  128x256 tile (full N); 4 waves 2x2, each 64x128.
// BK=64 stored as two 32-wide panels. A reg-staged f32->bf16 (or bf16 copy);
// B via global_load_lds.  [r9 config — best measured]
template <bool AF32>
__global__ __launch_bounds__(256) void mfma_gemm_kernel(const float* __restrict__ Af,
                                                        const unsigned short* __restrict__ Ab,
                                                        const unsigned short* __restrict__ WT,
                                                        float* __restrict__ C, int M,
                                                        int lda, int ldb, int kvalid, int ksteps) {
  __shared__ unsigned short As[2 * 128 * 32];   // panel kk at + kk*4096
  __shared__ unsigned short Bs[2 * 256 * 32];   // panel kk at + kk*8192
  const int bm = blockIdx.x * 128;
  const int tid = threadIdx.x, wave = tid >> 6, lane = tid & 63;
  const int wr = wave >> 1, wc = wave & 1;
  const int lhi = lane >> 4, llo = lane & 15;
  const int arow = tid >> 1, ahalf = tid & 1;   // ahalf = k-panel; 32 k-elems/thread
  f32x4 acc[4][8] = {};

  for (int st = 0; st < ksteps; st++) {
    const int k0 = st * 64;
    // ---- stage B: 256 cols x 64 k bf16 = 2048 chunks of 16B, 8 per thread
#pragma unroll
    for (int it = 0; it < 8; it++) {
      int c = it * 256 + wave * 64 + lane;         // 0..2047, LDS-linear
      int kk = c >> 10, r = (c >> 2) & 255, cb = c & 3;
      gload_lds16(WT + (size_t)r * ldb + k0 + kk * 32 + cb * 8, Bs + (size_t)c * 8);
    }
    // ---- stage A: row=arow, panel=ahalf, k in [k0+ahalf*32, +32)
    {
      int gr = bm + arow;
      int gk = k0 + ahalf * 32;
      unsigned short* dstp = As + ahalf * 4096 + arow * 32;
      if (AF32) {
        float f[32];
        if (gr < M && gk + 32 <= kvalid) {
          const float4* ap = (const float4*)(Af + (size_t)gr * lda + gk);
#pragma unroll
          for (int j = 0; j < 8; j++) {
            float4 v = ap[j];
            f[4 * j] = v.x; f[4 * j + 1] = v.y; f[4 * j + 2] = v.z; f[4 * j + 3] = v.w;
          }
        } else {
          const float* ap = Af + (size_t)gr * lda + gk;
#pragma unroll
          for (int j = 0; j < 32; j++)
            f[j] = (gr < M && gk + j < kvalid) ? ap[j] : 0.f;
        }
#pragma unroll
        for (int j = 0; j < 4; j++) {
          uint4 p;
          p.x = packbf(f[8 * j + 0], f[8 * j + 1]); p.y = packbf(f[8 * j + 2], f[8 * j + 3]);
          p.z = packbf(f[8 * j + 4], f[8 * j + 5]); p.w = packbf(f[8 * j + 6], f[8 * j + 7]);
          *(uint4*)(dstp + j * 8) = p;
        }
      } else {
        const uint4* ap = (const uint4*)(Ab + (size_t)gr * lda + gk);
#pragma unroll
        for (int j = 0; j < 4; j++) ((uint4*)dstp)[j] = ap[j];
      }
    }
    __syncthreads();   // drain vmcnt (gload_lds) + lgkmcnt (ds_write)

#pragma unroll
    for (int kk = 0; kk < 2; kk++) {
      s16x8 a[4], b[8];
#pragma unroll
      for (int mt = 0; mt < 4; mt++)
        a[mt] = *(const s16x8*)&As[kk * 4096 + (wr * 64 + mt * 16 + llo) * 32 + lhi * 8];
#pragma unroll
      for (int nt = 0; nt < 8; nt++)
        b[nt] = *(const s16x8*)&Bs[kk * 8192 + (wc * 128 + nt * 16 + llo) * 32 + lhi * 8];
#pragma unroll
      for (int mt = 0; mt < 4; mt++)
#pragma unroll
        for (int nt = 0; nt < 8; nt++)
          acc[mt][nt] = __builtin_amdgcn_mfma_f32_16x16x32_bf16(a[mt], b[nt], acc[mt][nt], 0, 0, 0);
    }
    __syncthreads();
  }

  // C/D layout: col = lane&15, row = (lane>>4)*4 + q
#pragma unroll
  for (int mt = 0; mt < 4; mt++) {
#pragma unroll
    for (int q = 0; q < 4; q++) {
      int row = bm + wr * 64 + mt * 16 + lhi * 4 + q;
      if (row < M) {
#pragma unroll
        for (int nt = 0; nt < 8; nt++)
          C[(size_t)row * 256 + wc * 128 + nt * 16 + llo] = acc[mt][nt][q];
      }
    }
  }
}

// per-graph fused CSR build (layer 0 only): count -> scan -> fill, all in LDS.
__global__ __launch_bounds__(1024) void csr_graph_kernel(const int* __restrict__ src,
                                                         const int* __restrict__ dst,
                                                         int n,
                                                         int* __restrict__ deg,
                                                         int* __restrict__ offs,
                                                         int* __restrict__ eid) {
  __shared__ int sdeg[1024];
  __shared__ int soff[1024];
  __shared__ int scur[1024];
  __shared__ int spart[1024];
  const int g = blockIdx.x, tid = threadIdx.x;
  sdeg[tid] = 0;
  __syncthreads();
  const int e0 = g * EPG_;
  for (int e = tid; e < EPG_; e += 1024)
    atomicAdd(&sdeg[dst[e0 + e] - g * n], 1);
  __syncthreads();
  int v = (tid < n) ? sdeg[tid] : 0;
  spart[tid] = v;
  __syncthreads();
  for (int ofs = 1; ofs < 1024; ofs <<= 1) {
    int t = (tid >= ofs) ? spart[tid - ofs] : 0;
    __syncthreads();
    spart[tid] += t;
    __syncthreads();
  }
  if (tid < n) {
    soff[tid] = spart[tid] - sdeg[tid];   // exclusive prefix
    scur[tid] = 0;
    deg[g * n + tid] = sdeg[tid];
    offs[g * n + tid] = g * EPG_ + soff[tid];
  }
  __syncthreads();
  for (int e = tid; e < EPG_; e += 1024) {
    int ge = e0 + e;
    int d = dst[ge] - g * n;
    int p = atomicAdd(&scur[d], 1);
    eid[g * EPG_ + soff[d] + p] = src[ge];
  }
}

// fused: agg (CSR gather) -> mean -> +bl +Z -> relu -> X; T = x·wrel; R = x·wroot.
__global__ void agg_sage_dots_kernel(const float* __restrict__ Y,
                                     const int* __restrict__ eid, const int* __restrict__ offs,
                                     const int* __restrict__ deg,
                                     const float* __restrict__ bl,
                                     const float* __restrict__ wrel, const float* __restrict__ wroot,
                                     float* __restrict__ X, float* __restrict__ T,
                                     float* __restrict__ R, int M) {
  int wid = threadIdx.x >> 6, lane = threadIdx.x & 63;
  int i = blockIdx.x * 4 + wid;
  if (i >= M) return;
  int d = deg[i], o = offs[i];
  float a0 = 0.f, a1 = 0.f;
  for (int j = 0; j < d; j++) {
    int s = eid[o + j];
    a0 += Y[(size_t)s * 256 + lane];
    a1 += Y[(size_t)s * 256 + 64 + lane];
  }
  float ic = 1.f / fmaxf((float)d, 1.f);
  float v0 = a0 * ic + bl[lane] + Y[(size_t)i * 256 + 128 + lane];
  float v1 = a1 * ic + bl[64 + lane] + Y[(size_t)i * 256 + 192 + lane];
  v0 = fmaxf(v0, 0.f); v1 = fmaxf(v1, 0.f);
  X[(size_t)i * 128 + lane] = v0;
  X[(size_t)i * 128 + 64 + lane] = v1;
  float t = v0 * wrel[lane] + v1 * wrel[64 + lane];
  float r = v0 * wroot[lane] + v1 * wroot[64 + lane];
#pragma unroll
  for (int off = 32; off > 0; off >>= 1) {
    t += __shfl_down(t, off);
    r += __shfl_down(r, off);
  }
  if (lane == 0) { T[i] = t; R[i] = r; }
}

// fused per-graph tail: score via CSR -> bitonic top-k -> gate/gather(NXB)
// -> f32 readout into H -> build NEXT-layer CSR in LDS (r12-verified logic).
template <int NP>
__global__ __launch_bounds__(1024) void pool_kernel(
    const float* __restrict__ X, const float* __restrict__ T, const float* __restrict__ R,
    const float* __restrict__ brel,
    const int* __restrict__ deg, const int* __restrict__ offs, const int* __restrict__ eid,
    int n, int k,
    unsigned short* __restrict__ NXB,
    int* __restrict__ degN, int* __restrict__ offsN, int* __restrict__ eidN,
    float* __restrict__ H) {
  __shared__ float val[NP];
  __shared__ int   ind[NP];
  __shared__ int   lmap[NP];
  __shared__ float gate[256];
  __shared__ int   sdegN[256];
  __shared__ int   soffN[256];
  __shared__ float redmx[8][128];
  __shared__ float redsm[8][128];
  const int g = blockIdx.x, tid = threadIdx.x, nthr = blockDim.x;
  float b0 = brel[0];
  // scores
  for (int i = tid; i < NP; i += nthr) {
    lmap[i] = -1;
    float v = -FLT_MAX;
    if (i < n) {
      int gi = g * n + i;
      int dd = deg[gi], o = offs[gi];
      float s = 0.f;
      for (int j = 0; j < dd; j++) s += T[eid[o + j]];
      v = s + R[gi] + b0;
    }
    val[i] = v;
    ind[i] = i;
  }
  __syncthreads();
  // bitonic sort desc
  for (int kk = 2; kk <= NP; kk <<= 1) {
    for (int j = kk >> 1; j > 0; j >>= 1) {
      for (int i = tid; i < NP; i += nthr) {
        int ixj = i ^ j;
        if (ixj > i) {
          bool desc = ((i & kk) == 0);
          float vi = val[i], vj = val[ixj];
          if (desc ? (vi < vj) : (vi > vj)) {
            val[i] = vj; val[ixj] = vi;
            int tmp = ind[i]; ind[i] = ind[ixj]; ind[ixj] = tmp;
          }
        }
      }
      __syncthreads();
    }
  }
  for (int t = tid; t < k; t += nthr) {
    lmap[ind[t]] = t;
    gate[t] = tanhf(val[t]);
  }
  __syncthreads();
  // gather + gate -> NXB (bf16)
  for (int idx = tid; idx < k * 128; idx += nthr) {
    int t = idx >> 7, c = idx & 127;
    float v = X[(size_t)(g * n + ind[t]) * 128 + c] * gate[t];
    NXB[(size_t)(g * k + t) * 128 + c] = (unsigned short)f2bf1(v);
  }
  // readout in f32
  {
    int c = tid & 127, seg = tid >> 7;
    float mxv = -FLT_MAX, smv = 0.f;
    for (int t = seg; t < k; t += 8) {
      float v = X[(size_t)(g * n + ind[t]) * 128 + c] * gate[t];
      mxv = fmaxf(mxv, v);
      smv += v;
    }
    redmx[seg][c] = mxv;
    redsm[seg][c] = smv;
  }
  __syncthreads();
  if (tid < 128) {
    float Mv = redmx[0][tid], S = redsm[0][tid];
#pragma unroll
    for (int s2 = 1; s2 < 8; s2++) { Mv = fmaxf(Mv, redmx[s2][tid]); S += redsm[s2][tid]; }
    H[g * 256 + tid] += Mv;
    H[g * 256 + 128 + tid] += S / (float)k;
  }
  // build next-layer CSR (nodes g*k+slot; srcs remapped through lmap)
  if (degN) {
    for (int t = tid; t < k; t += nthr) sdegN[t] = 0;
    __syncthreads();
    for (int d = tid; d < n; d += nthr) {
      int ld = lmap[d];
      if (ld < 0) continue;
      int gd = g * n + d, dd = deg[gd], o = offs[gd];
      int cnt = 0;
      for (int j = 0; j < dd; j++)
        cnt += (lmap[eid[o + j] - g * n] >= 0);
      sdegN[ld] = cnt;            // unique slot per d — no atomic
    }
    __syncthreads();
    if (tid == 0) {
      int run = 0;
      for (int t = 0; t < k; t++) { soffN[t] = run; run += sdegN[t]; }
    }
    __syncthreads();
    for (int d = tid; d < n; d += nthr) {
      int ld = lmap[d];
      if (ld < 0) continue;
      int gd = g * n + d, dd = deg[gd], o = offs[gd];
      int p = 0;
      for (int j = 0; j < dd; j++) {
        int ls = lmap[eid[o + j] - g * n];
        if (ls >= 0) eidN[g * EPG_ + soffN[ld] + (p++)] = g * k + ls;
      }
      degN[g * k + ld] = p;
      offsN[g * k + ld] = g * EPG_ + soffN[ld];
    }
  }
}

__global__ void head_kernel(const float* __restrict__ H, const int* __restrict__ gpp,
                            const float* __restrict__ lin1_w, const float* __restrict__ lin1_b,
                            const float* __restrict__ lin2_w, const float* __restrict__ lin2_b,
                            const float* __restrict__ grade_w, const float* __restrict__ grade_b,
                            const float* __restrict__ haz_w, const float* __restrict__ haz_b,
                            float* __restrict__ out) {
  __shared__ float pooled[P_][256];
  __shared__ float h1[P_][NHID_];
  __shared__ float feats[P_][GDIM_];
  __shared__ int off[P_ + 1];
  int tid = threadIdx.x;
  if (tid == 0) {
    off[0] = 0;
    for (int p = 0; p < P_; p++) off[p + 1] = min(off[p] + gpp[p], G_);
  }
  __syncthreads();
  for (int idx = tid; idx < P_ * 256; idx += blockDim.x) {
    int p = idx >> 8, c = idx & 255;
    int a = off[p], b = (p == P_ - 1) ? G_ : off[p + 1];
    float s = 0.f;
    for (int gq = a; gq < b; gq++) s += H[gq * 256 + c];
    pooled[p][c] = s / (float)gpp[p];
  }
  __syncthreads();
  for (int idx = tid; idx < P_ * NHID_; idx += blockDim.x) {
    int p = idx >> 7, o = idx & 127;
    float acc = lin1_b[o];
    for (int c = 0; c < 256; c++) acc += pooled[p][c] * lin1_w[c * NHID_ + o];
    h1[p][o] = fmaxf(acc, 0.f);
  }
  __syncthreads();
  for (int idx = tid; idx < P_ * GDIM_; idx += blockDim.x) {
    int p = idx / GDIM_, o = idx % GDIM_;
    float acc = lin2_b[o];
    for (int c = 0; c < NHID_; c++) acc += h1[p][c] * lin2_w[c * GDIM_ + o];
    float f = fmaxf(acc, 0.f);
    feats[p][o] = f;
    out[p * GDIM_ + o] = f;
  }
  __syncthreads();
  if (tid < P_) {
    int p = tid;
    float l[3];
    float mx = -FLT_MAX;
    for (int j = 0; j < 3; j++) {
      float acc = grade_b[j];
      for (int c = 0; c < GDIM_; c++) acc += feats[p][c] * grade_w[c * 3 + j];
      l[j] = acc;
      mx = fmaxf(mx, acc);
    }
    float se = 0.f;
    for (int j = 0; j < 3; j++) se += expf(l[j] - mx);
    float lse = mx + logf(se);
    for (int j = 0; j < 3; j++) out[P_ * GDIM_ + p * 3 + j] = l[j] - lse;
    float z = haz_b[0];
    for (int c = 0; c < GDIM_; c++) z += feats[p][c] * haz_w[c];
    out[P_ * GDIM_ + P_ * 3 + p] = 6.f / (1.f + expf(-z)) - 3.f;
  }
}

// ---------------- launch ----------------
extern "C" void kernel_launch(void* const* d_in, const int* in_sizes, int n_in,
                              void* d_out, int out_size, void* d_ws, size_t ws_size,
                              hipStream_t stream) {
  (void)in_sizes; (void)n_in; (void)out_size; (void)ws_size;
  const float* x  = (const float*)d_in[0];
  const int* ei   = (const int*)d_in[1];
  const int* gpp  = (const int*)d_in[2];
  const float* c_wl[3]    = {(const float*)d_in[3],  (const float*)d_in[9],  (const float*)d_in[15]};
  const float* c_bl[3]    = {(const float*)d_in[4],  (const float*)d_in[10], (const float*)d_in[16]};
  const float* c_wr[3]    = {(const float*)d_in[5],  (const float*)d_in[11], (const float*)d_in[17]};
  const float* p_wrel[3]  = {(const float*)d_in[6],  (const float*)d_in[12], (const float*)d_in[18]};
  const float* p_brel[3]  = {(const float*)d_in[7],  (const float*)d_in[13], (const float*)d_in[19]};
  const float* p_wroot[3] = {(const float*)d_in[8],  (const float*)d_in[14], (const float*)d_in[20]};
  const float* lin1_w = (const float*)d_in[21];
  const float* lin1_b = (const float*)d_in[22];
  const float* lin2_w = (const float*)d_in[23];
  const float* lin2_b = (const float*)d_in[24];
  const float* grade_w = (const float*)d_in[25];
  const float* grade_b = (const float*)d_in[26];
  const float* haz_w = (const float*)d_in[27];
  const float* haz_b = (const float*)d_in[28];

  char* wsb = (char*)d_ws;
  size_t off = 0;
  auto alloc = [&](size_t bytes) -> void* {
    void* p = wsb + off;
    off += (bytes + 255) & ~(size_t)255;
    return p;
  };
  int*            SCALE = (int*)alloc(64 * 4);
  unsigned short* WT0   = (unsigned short*)alloc((size_t)256 * KPAD_ * 2);
  unsigned short* WT1   = (unsigned short*)alloc((size_t)256 * 128 * 2);
  unsigned short* WT2   = (unsigned short*)alloc((size_t)256 * 128 * 2);
  float*          YZ    = (float*)alloc((size_t)M0_ * 256 * 4);
  float*          H     = (float*)alloc((size_t)G_ * 256 * 4);
  float* X     = (float*)alloc((size_t)M0_ * 128 * 4);
  unsigned short* NXB = (unsigned short*)alloc((size_t)MPAD1_ * 128 * 2);
  float* T     = (float*)alloc((size_t)M0_ * 4);
  float* R     = (float*)alloc((size_t)M0_ * 4);
  int*   DEG0  = (int*)alloc((size_t)M0_ * 4);
  int*   OFF0  = (int*)alloc((size_t)M0_ * 4);
  int*   EID0  = (int*)alloc((size_t)NEDGE * 4);
  int*   DEG1  = (int*)alloc((size_t)M1_ * 4);
  int*   OFF1  = (int*)alloc((size_t)M1_ * 4);
  int*   EID1  = (int*)alloc((size_t)NEDGE * 4);

  const int* src0 = ei;
  const int* dst0 = ei + NEDGE;

  hipMemsetAsync(H, 0, G_ * 256 * sizeof(float), stream);
  hipMemsetAsync(SCALE, 0, 12 * sizeof(int), stream);

  // ---- setup ----
  colmax_kernel<<<128, 256, 0, stream>>>(x, SCALE);
  build_wt0_kernel<<<(256 * KPAD_ + 255) / 256, 256, 0, stream>>>(c_wl[0], c_wr[0], SCALE, WT0);
  build_wt12_kernel<<<(2 * 256 * 128 + 255) / 256, 256, 0, stream>>>(c_wl[1], c_wr[1], c_wl[2], c_wr[2], WT1, WT2);

  // ---- layer 0 ----
  csr_graph_kernel<<<G_, 1024, 0, stream>>>(src0, dst0, N0_, DEG0, OFF0, EID0);
  mfma_gemm_kernel<true><<<MPAD0_ / 128, 256, 0, stream>>>(x, nullptr, WT0, YZ, M0_, FEAT_, KPAD_, FEAT_, KPAD_ / 64);
  agg_sage_dots_kernel<<<(M0_ + 3) / 4, 256, 0, stream>>>(YZ, EID0, OFF0, DEG0, c_bl[0], p_wrel[0], p_wroot[0], X, T, R, M0_);
  pool_kernel<1024><<<G_, 1024, 0, stream>>>(X, T, R, p_brel[0], DEG0, OFF0, EID0,
                                             N0_, K0_, NXB, DEG1, OFF1, EID1, H);

  // ---- layer 1 ----
  mfma_gemm_kernel<false><<<MPAD1_ / 128, 256, 0, stream>>>(nullptr, NXB, WT1, YZ, M1_, 128, 128, 128, 2);
  agg_sage_dots_kernel<<<(M1_ + 3) / 4, 256, 0, stream>>>(YZ, EID1, OFF1, DEG1, c_bl[1], p_wrel[1], p_wroot[1], X, T, R, M1_);
  pool_kernel<256><<<G_, 1024, 0, stream>>>(X, T, R, p_brel[1], DEG1, OFF1, EID1,
                                            K0_, K1_, NXB, DEG0, OFF0, EID0, H);

  // ---- layer 2 ----
  mfma_gemm_kernel<false><<<MPAD2_ / 128, 256, 0, stream>>>(nullptr, NXB, WT2, YZ, M2_, 128, 128, 128, 2);
  agg_sage_dots_kernel<<<(M2_ + 3) / 4, 256, 0, stream>>>(YZ, EID0, OFF0, DEG0, c_bl[2], p_wrel[2], p_wroot[2], X, T, R, M2_);
  pool_kernel<64><<<G_, 1024, 0, stream>>>(X, T, R, p_brel[2], DEG0, OFF0, EID0,
                                           K1_, K2_, NXB, nullptr, nullptr, nullptr, H);

  // ---- head ----
  head_kernel<<<1, 256, 0, stream>>>(H, gpp, lin1_w, lin1_b, lin2_w, lin2_b,
                                     grade_w, grade_b, haz_w, haz_b, (float*)d_out);
}

// Round 17
// 270.816 us; speedup vs baseline: 1.2380x; 1.0078x over previous
//
#include <hip/hip_runtime.h>
#include <math.h>
#include <cfloat>

// ---------------- problem constants ----------------
#define G_    50
#define N0_   1000
#define NEDGE 200000
#define EPG_  (NEDGE/G_)   // 4000 edges per graph (contiguous slots)
#define P_    10
#define FEAT_ 1036
#define NHID_ 128
#define GDIM_ 32
#define K0_   200
#define K1_   40
#define K2_   8
#define M0_   (G_*N0_)     // 50000
#define M1_   (G_*K0_)     // 10000
#define M2_   (G_*K1_)     // 2000

#define KPAD_ 1088         // 1036 padded to multiple of 64
#define MPAD0_ 50048       // mult of 128
#define MPAD1_ 10112       // mult of 128
#define MPAD2_ 2048        // mult of 128

typedef __attribute__((ext_vector_type(8))) short s16x8;
typedef __attribute__((ext_vector_type(4))) float f32x4;

__device__ __forceinline__ unsigned f2bf1(float f) {   // bf16 bits, RNE
  unsigned u = __float_as_uint(f);
  return (u + 0x7FFFu + ((u >> 16) & 1u)) >> 16;
}
__device__ __forceinline__ unsigned packbf(float a, float b) {
  return f2bf1(a) | (f2bf1(b) << 16);
}

__device__ __forceinline__ void gload_lds16(const void* g, void* l) {
  __builtin_amdgcn_global_load_lds((const __attribute__((address_space(1))) void*)g,
                                   (__attribute__((address_space(3))) void*)l, 16, 0, 0);
}

// ---------------- kernels ----------------

// row-major colmax
__global__ void colmax_kernel(const float* __restrict__ x, int* __restrict__ scale_i) {
  int tid = threadIdx.x, wave = tid >> 6, lane = tid & 63;
  float mx[12];
#pragma unroll
  for (int j = 0; j < 12; j++) mx[j] = 0.f;
  for (int r = blockIdx.x * 256 + tid; r < M0_; r += gridDim.x * 256) {
    const float4* p = (const float4*)(x + (size_t)r * FEAT_);
    float4 a = p[0], b = p[1], c = p[2];
    mx[0] = fmaxf(mx[0], a.x); mx[1] = fmaxf(mx[1], a.y);
    mx[2] = fmaxf(mx[2], a.z); mx[3] = fmaxf(mx[3], a.w);
    mx[4] = fmaxf(mx[4], b.x); mx[5] = fmaxf(mx[5], b.y);
    mx[6] = fmaxf(mx[6], b.z); mx[7] = fmaxf(mx[7], b.w);
    mx[8] = fmaxf(mx[8], c.x); mx[9] = fmaxf(mx[9], c.y);
    mx[10] = fmaxf(mx[10], c.z); mx[11] = fmaxf(mx[11], c.w);
  }
#pragma unroll
  for (int off = 32; off > 0; off >>= 1)
#pragma unroll
    for (int j = 0; j < 12; j++) mx[j] = fmaxf(mx[j], __shfl_down(mx[j], off));
  __shared__ float red[4][12];
  if (lane == 0)
#pragma unroll
    for (int j = 0; j < 12; j++) red[wave][j] = mx[j];
  __syncthreads();
  if (tid < 12) {
    float m = fmaxf(fmaxf(red[0][tid], red[1][tid]), fmaxf(red[2][tid], red[3][tid]));
    atomicMax(scale_i + tid, __float_as_int(m));
  }
}

__global__ void build_wt0_kernel(const float* __restrict__ wl, const float* __restrict__ wr,
                                 const int* __restrict__ scale_i, unsigned short* __restrict__ WT) {
  int idx = blockIdx.x * blockDim.x + threadIdx.x;
  if (idx >= 256 * KPAD_) return;
  int c = idx / KPAD_, j = idx % KPAD_;
  float w = 0.f;
  if (j < FEAT_) {
    w = (c < NHID_) ? wl[j * NHID_ + c] : wr[j * NHID_ + (c - NHID_)];
    if (j < 12) w *= 1.0f / __int_as_float(scale_i[j]);
  }
  WT[idx] = (unsigned short)f2bf1(w);
}

__global__ void build_wt12_kernel(const float* __restrict__ wl1, const float* __restrict__ wr1,
                                  const float* __restrict__ wl2, const float* __restrict__ wr2,
                                  unsigned short* __restrict__ WTA, unsigned short* __restrict__ WTB) {
  int idx = blockIdx.x * blockDim.x + threadIdx.x;
  if (idx >= 2 * 256 * 128) return;
  int l = idx >> 15, r = idx & 32767;
  int c = r >> 7, j = r & 127;
  const float* wl = l ? wl2 : wl1;
  const float* wr = l ? wr2 : wr1;
  float w = (c < NHID_) ? wl[j * NHID_ + c] : wr[j * NHID_ + (c - NHID_)];
  (l ? WTB : WTA)[r] = (unsigned short)f2bf1(w);
}

// C[M x 256] = A @ WT^T.  128x256 tile (full N); 4 waves 2x2, each 64x128.
// BK=64 stored as two 32-wide panels. A reg-staged f32->bf16 (or bf16 copy);
// B via global_load_lds.  [r9 config — best measured]
template <bool AF32>
__global__ __launch_bounds__(256) void mfma_gemm_kernel(const float* __restrict__ Af,
                                                        const unsigned short* __restrict__ Ab,
                                                        const unsigned short* __restrict__ WT,
                                                        float* __restrict__ C, int M,
                                                        int lda, int ldb, int kvalid, int ksteps) {
  __shared__ unsigned short As[2 * 128 * 32];   // panel kk at + kk*4096
  __shared__ unsigned short Bs[2 * 256 * 32];   // panel kk at + kk*8192
  const int bm = blockIdx.x * 128;
  const int tid = threadIdx.x, wave = tid >> 6, lane = tid & 63;
  const int wr = wave >> 1, wc = wave & 1;
  const int lhi = lane >> 4, llo = lane & 15;
  const int arow = tid >> 1, ahalf = tid & 1;   // ahalf = k-panel; 32 k-elems/thread
  f32x4 acc[4][8] = {};

  for (int st = 0; st < ksteps; st++) {
    const int k0 = st * 64;
    // ---- stage B: 256 cols x 64 k bf16 = 2048 chunks of 16B, 8 per thread
#pragma unroll
    for (int it = 0; it < 8; it++) {
      int c = it * 256 + wave * 64 + lane;         // 0..2047, LDS-linear
      int kk = c >> 10, r = (c >> 2) & 255, cb = c & 3;
      gload_lds16(WT + (size_t)r * ldb + k0 + kk * 32 + cb * 8, Bs + (size_t)c * 8);
    }
    // ---- stage A: row=arow, panel=ahalf, k in [k0+ahalf*32, +32)
    {
      int gr = bm + arow;
      int gk = k0 + ahalf * 32;
      unsigned short* dstp = As + ahalf * 4096 + arow * 32;
      if (AF32) {
        float f[32];
        if (gr < M && gk + 32 <= kvalid) {
          const float4* ap = (const float4*)(Af + (size_t)gr * lda + gk);
#pragma unroll
          for (int j = 0; j < 8; j++) {
            float4 v = ap[j];
            f[4 * j] = v.x; f[4 * j + 1] = v.y; f[4 * j + 2] = v.z; f[4 * j + 3] = v.w;
          }
        } else {
          const float* ap = Af + (size_t)gr * lda + gk;
#pragma unroll
          for (int j = 0; j < 32; j++)
            f[j] = (gr < M && gk + j < kvalid) ? ap[j] : 0.f;
        }
#pragma unroll
        for (int j = 0; j < 4; j++) {
          uint4 p;
          p.x = packbf(f[8 * j + 0], f[8 * j + 1]); p.y = packbf(f[8 * j + 2], f[8 * j + 3]);
          p.z = packbf(f[8 * j + 4], f[8 * j + 5]); p.w = packbf(f[8 * j + 6], f[8 * j + 7]);
          *(uint4*)(dstp + j * 8) = p;
        }
      } else {
        const uint4* ap = (const uint4*)(Ab + (size_t)gr * lda + gk);
#pragma unroll
        for (int j = 0; j < 4; j++) ((uint4*)dstp)[j] = ap[j];
      }
    }
    __syncthreads();   // drain vmcnt (gload_lds) + lgkmcnt (ds_write)

#pragma unroll
    for (int kk = 0; kk < 2; kk++) {
      s16x8 a[4], b[8];
#pragma unroll
      for (int mt = 0; mt < 4; mt++)
        a[mt] = *(const s16x8*)&As[kk * 4096 + (wr * 64 + mt * 16 + llo) * 32 + lhi * 8];
#pragma unroll
      for (int nt = 0; nt < 8; nt++)
        b[nt] = *(const s16x8*)&Bs[kk * 8192 + (wc * 128 + nt * 16 + llo) * 32 + lhi * 8];
#pragma unroll
      for (int mt = 0; mt < 4; mt++)
#pragma unroll
        for (int nt = 0; nt < 8; nt++)
          acc[mt][nt] = __builtin_amdgcn_mfma_f32_16x16x32_bf16(a[mt], b[nt], acc[mt][nt], 0, 0, 0);
    }
    __syncthreads();
  }

  // C/D layout: col = lane&15, row = (lane>>4)*4 + q
#pragma unroll
  for (int mt = 0; mt < 4; mt++) {
#pragma unroll
    for (int q = 0; q < 4; q++) {
      int row = bm + wr * 64 + mt * 16 + lhi * 4 + q;
      if (row < M) {
#pragma unroll
        for (int nt = 0; nt < 8; nt++)
          C[(size_t)row * 256 + wc * 128 + nt * 16 + llo] = acc[mt][nt][q];
      }
    }
  }
}

// per-graph fused CSR build (layer 0 only): count -> scan -> fill, all in LDS.
__global__ __launch_bounds__(1024) void csr_graph_kernel(const int* __restrict__ src,
                                                         const int* __restrict__ dst,
                                                         int n,
                                                         int* __restrict__ deg,
                                                         int* __restrict__ offs,
                                                         int* __restrict__ eid) {
  __shared__ int sdeg[1024];
  __shared__ int soff[1024];
  __shared__ int scur[1024];
  __shared__ int spart[1024];
  const int g = blockIdx.x, tid = threadIdx.x;
  sdeg[tid] = 0;
  __syncthreads();
  const int e0 = g * EPG_;
  for (int e = tid; e < EPG_; e += 1024)
    atomicAdd(&sdeg[dst[e0 + e] - g * n], 1);
  __syncthreads();
  int v = (tid < n) ? sdeg[tid] : 0;
  spart[tid] = v;
  __syncthreads();
  for (int ofs = 1; ofs < 1024; ofs <<= 1) {
    int t = (tid >= ofs) ? spart[tid - ofs] : 0;
    __syncthreads();
    spart[tid] += t;
    __syncthreads();
  }
  if (tid < n) {
    soff[tid] = spart[tid] - sdeg[tid];   // exclusive prefix
    scur[tid] = 0;
    deg[g * n + tid] = sdeg[tid];
    offs[g * n + tid] = g * EPG_ + soff[tid];
  }
  __syncthreads();
  for (int e = tid; e < EPG_; e += 1024) {
    int ge = e0 + e;
    int d = dst[ge] - g * n;
    int p = atomicAdd(&scur[d], 1);
    eid[g * EPG_ + soff[d] + p] = src[ge];
  }
}

// fused: agg (CSR gather) -> mean -> +bl +Z -> relu -> X; T = x·wrel; R = x·wroot.
__global__ void agg_sage_dots_kernel(const float* __restrict__ Y,
                                     const int* __restrict__ eid, const int* __restrict__ offs,
                                     const int* __restrict__ deg,
                                     const float* __restrict__ bl,
                                     const float* __restrict__ wrel, const float* __restrict__ wroot,
                                     float* __restrict__ X, float* __restrict__ T,
                                     float* __restrict__ R, int M) {
  int wid = threadIdx.x >> 6, lane = threadIdx.x & 63;
  int i = blockIdx.x * 4 + wid;
  if (i >= M) return;
  int d = deg[i], o = offs[i];
  float a0 = 0.f, a1 = 0.f;
  for (int j = 0; j < d; j++) {
    int s = eid[o + j];
    a0 += Y[(size_t)s * 256 + lane];
    a1 += Y[(size_t)s * 256 + 64 + lane];
  }
  float ic = 1.f / fmaxf((float)d, 1.f);
  float v0 = a0 * ic + bl[lane] + Y[(size_t)i * 256 + 128 + lane];
  float v1 = a1 * ic + bl[64 + lane] + Y[(size_t)i * 256 + 192 + lane];
  v0 = fmaxf(v0, 0.f); v1 = fmaxf(v1, 0.f);
  X[(size_t)i * 128 + lane] = v0;
  X[(size_t)i * 128 + 64 + lane] = v1;
  float t = v0 * wrel[lane] + v1 * wrel[64 + lane];
  float r = v0 * wroot[lane] + v1 * wroot[64 + lane];
#pragma unroll
  for (int off = 32; off > 0; off >>= 1) {
    t += __shfl_down(t, off);
    r += __shfl_down(r, off);
  }
  if (lane == 0) { T[i] = t; R[i] = r; }
}

// fused per-graph tail: score via CSR -> bitonic top-k -> gate/gather(NXB)
// -> f32 readout into H -> build NEXT-layer CSR in LDS (r12-verified logic).
template <int NP>
__global__ __launch_bounds__(1024) void pool_kernel(
    const float* __restrict__ X, const float* __restrict__ T, const float* __restrict__ R,
    const float* __restrict__ brel,
    const int* __restrict__ deg, const int* __restrict__ offs, const int* __restrict__ eid,
    int n, int k,
    unsigned short* __restrict__ NXB,
    int* __restrict__ degN, int* __restrict__ offsN, int* __restrict__ eidN,
    float* __restrict__ H) {
  __shared__ float val[NP];
  __shared__ int   ind[NP];
  __shared__ int   lmap[NP];
  __shared__ float gate[256];
  __shared__ int   sdegN[256];
  __shared__ int   soffN[256];
  __shared__ float redmx[8][128];
  __shared__ float redsm[8][128];
  const int g = blockIdx.x, tid = threadIdx.x, nthr = blockDim.x;
  float b0 = brel[0];
  // scores
  for (int i = tid; i < NP; i += nthr) {
    lmap[i] = -1;
    float v = -FLT_MAX;
    if (i < n) {
      int gi = g * n + i;
      int dd = deg[gi], o = offs[gi];
      float s = 0.f;
      for (int j = 0; j < dd; j++) s += T[eid[o + j]];
      v = s + R[gi] + b0;
    }
    val[i] = v;
    ind[i] = i;
  }
  __syncthreads();
  // bitonic sort desc
  for (int kk = 2; kk <= NP; kk <<= 1) {
    for (int j = kk >> 1; j > 0; j >>= 1) {
      for (int i = tid; i < NP; i += nthr) {
        int ixj = i ^ j;
        if (ixj > i) {
          bool desc = ((i & kk) == 0);
          float vi = val[i], vj = val[ixj];
          if (desc ? (vi < vj) : (vi > vj)) {
            val[i] = vj; val[ixj] = vi;
            int tmp = ind[i]; ind[i] = ind[ixj]; ind[ixj] = tmp;
          }
        }
      }
      __syncthreads();
    }
  }
  for (int t = tid; t < k; t += nthr) {
    lmap[ind[t]] = t;
    gate[t] = tanhf(val[t]);
  }
  __syncthreads();
  // gather + gate -> NXB (bf16)
  for (int idx = tid; idx < k * 128; idx += nthr) {
    int t = idx >> 7, c = idx & 127;
    float v = X[(size_t)(g * n + ind[t]) * 128 + c] * gate[t];
    NXB[(size_t)(g * k + t) * 128 + c] = (unsigned short)f2bf1(v);
  }
  // readout in f32
  {
    int c = tid & 127, seg = tid >> 7;
    float mxv = -FLT_MAX, smv = 0.f;
    for (int t = seg; t < k; t += 8) {
      float v = X[(size_t)(g * n + ind[t]) * 128 + c] * gate[t];
      mxv = fmaxf(mxv, v);
      smv += v;
    }
    redmx[seg][c] = mxv;
    redsm[seg][c] = smv;
  }
  __syncthreads();
  if (tid < 128) {
    float Mv = redmx[0][tid], S = redsm[0][tid];
#pragma unroll
    for (int s2 = 1; s2 < 8; s2++) { Mv = fmaxf(Mv, redmx[s2][tid]); S += redsm[s2][tid]; }
    H[g * 256 + tid] += Mv;
    H[g * 256 + 128 + tid] += S / (float)k;
  }
  // build next-layer CSR (nodes g*k+slot; srcs remapped through lmap)
  if (degN) {
    for (int t = tid; t < k; t += nthr) sdegN[t] = 0;
    __syncthreads();
    for (int d = tid; d < n; d += nthr) {
      int ld = lmap[d];
      if (ld < 0) continue;
      int gd = g * n + d, dd = deg[gd], o = offs[gd];
      int cnt = 0;
      for (int j = 0; j < dd; j++)
        cnt += (lmap[eid[o + j] - g * n] >= 0);
      sdegN[ld] = cnt;            // unique slot per d — no atomic
    }
    __syncthreads();
    if (tid == 0) {
      int run = 0;
      for (int t = 0; t < k; t++) { soffN[t] = run; run += sdegN[t]; }
    }
    __syncthreads();
    for (int d = tid; d < n; d += nthr) {
      int ld = lmap[d];
      if (ld < 0) continue;
      int gd = g * n + d, dd = deg[gd], o = offs[gd];
      int p = 0;
      for (int j = 0; j < dd; j++) {
        int ls = lmap[eid[o + j] - g * n];
        if (ls >= 0) eidN[g * EPG_ + soffN[ld] + (p++)] = g * k + ls;
      }
      degN[g * k + ld] = p;
      offsN[g * k + ld] = g * EPG_ + soffN[ld];
    }
  }
}

__global__ void head_kernel(const float* __restrict__ H, const int* __restrict__ gpp,
                            const float* __restrict__ lin1_w, const float* __restrict__ lin1_b,
                            const float* __restrict__ lin2_w, const float* __restrict__ lin2_b,
                            const float* __restrict__ grade_w, const float* __restrict__ grade_b,
                            const float* __restrict__ haz_w, const float* __restrict__ haz_b,
                            float* __restrict__ out) {
  __shared__ float pooled[P_][256];
  __shared__ float h1[P_][NHID_];
  __shared__ float feats[P_][GDIM_];
  __shared__ int off[P_ + 1];
  int tid = threadIdx.x;
  if (tid == 0) {
    off[0] = 0;
    for (int p = 0; p < P_; p++) off[p + 1] = min(off[p] + gpp[p], G_);
  }
  __syncthreads();
  for (int idx = tid; idx < P_ * 256; idx += blockDim.x) {
    int p = idx >> 8, c = idx & 255;
    int a = off[p], b = (p == P_ - 1) ? G_ : off[p + 1];
    float s = 0.f;
    for (int gq = a; gq < b; gq++) s += H[gq * 256 + c];
    pooled[p][c] = s / (float)gpp[p];
  }
  __syncthreads();
  for (int idx = tid; idx < P_ * NHID_; idx += blockDim.x) {
    int p = idx >> 7, o = idx & 127;
    float acc = lin1_b[o];
    for (int c = 0; c < 256; c++) acc += pooled[p][c] * lin1_w[c * NHID_ + o];
    h1[p][o] = fmaxf(acc, 0.f);
  }
  __syncthreads();
  for (int idx = tid; idx < P_ * GDIM_; idx += blockDim.x) {
    int p = idx / GDIM_, o = idx % GDIM_;
    float acc = lin2_b[o];
    for (int c = 0; c < NHID_; c++) acc += h1[p][c] * lin2_w[c * GDIM_ + o];
    float f = fmaxf(acc, 0.f);
    feats[p][o] = f;
    out[p * GDIM_ + o] = f;
  }
  __syncthreads();
  if (tid < P_) {
    int p = tid;
    float l[3];
    float mx = -FLT_MAX;
    for (int j = 0; j < 3; j++) {
      float acc = grade_b[j];
      for (int c = 0; c < GDIM_; c++) acc += feats[p][c] * grade_w[c * 3 + j];
      l[j] = acc;
      mx = fmaxf(mx, acc);
    }
    float se = 0.f;
    for (int j = 0; j < 3; j++) se += expf(l[j] - mx);
    float lse = mx + logf(se);
    for (int j = 0; j < 3; j++) out[P_ * GDIM_ + p * 3 + j] = l[j] - lse;
    float z = haz_b[0];
    for (int c = 0; c < GDIM_; c++) z += feats[p][c] * haz_w[c];
    out[P_ * GDIM_ + P_ * 3 + p] = 6.f / (1.f + expf(-z)) - 3.f;
  }
}

// ---------------- launch ----------------
extern "C" void kernel_launch(void* const* d_in, const int* in_sizes, int n_in,
                              void* d_out, int out_size, void* d_ws, size_t ws_size,
                              hipStream_t stream) {
  (void)in_sizes; (void)n_in; (void)out_size; (void)ws_size;
  const float* x  = (const float*)d_in[0];
  const int* ei   = (const int*)d_in[1];
  const int* gpp  = (const int*)d_in[2];
  const float* c_wl[3]    = {(const float*)d_in[3],  (const float*)d_in[9],  (const float*)d_in[15]};
  const float* c_bl[3]    = {(const float*)d_in[4],  (const float*)d_in[10], (const float*)d_in[16]};
  const float* c_wr[3]    = {(const float*)d_in[5],  (const float*)d_in[11], (const float*)d_in[17]};
  const float* p_wrel[3]  = {(const float*)d_in[6],  (const float*)d_in[12], (const float*)d_in[18]};
  const float* p_brel[3]  = {(const float*)d_in[7],  (const float*)d_in[13], (const float*)d_in[19]};
  const float* p_wroot[3] = {(const float*)d_in[8],  (const float*)d_in[14], (const float*)d_in[20]};
  const float* lin1_w = (const float*)d_in[21];
  const float* lin1_b = (const float*)d_in[22];
  const float* lin2_w = (const float*)d_in[23];
  const float* lin2_b = (const float*)d_in[24];
  const float* grade_w = (const float*)d_in[25];
  const float* grade_b = (const float*)d_in[26];
  const float* haz_w = (const float*)d_in[27];
  const float* haz_b = (const float*)d_in[28];

  char* wsb = (char*)d_ws;
  size_t off = 0;
  auto alloc = [&](size_t bytes) -> void* {
    void* p = wsb + off;
    off += (bytes + 255) & ~(size_t)255;
    return p;
  };
  int*            SCALE = (int*)alloc(64 * 4);
  unsigned short* WT0   = (unsigned short*)alloc((size_t)256 * KPAD_ * 2);
  unsigned short* WT1   = (unsigned short*)alloc((size_t)256 * 128 * 2);
  unsigned short* WT2   = (unsigned short*)alloc((size_t)256 * 128 * 2);
  float*          YZ    = (float*)alloc((size_t)M0_ * 256 * 4);
  float*          H     = (float*)alloc((size_t)G_ * 256 * 4);
  float* X     = (float*)alloc((size_t)M0_ * 128 * 4);
  unsigned short* NXB = (unsigned short*)alloc((size_t)MPAD1_ * 128 * 2);
  float* T     = (float*)alloc((size_t)M0_ * 4);
  float* R     = (float*)alloc((size_t)M0_ * 4);
  int*   DEG0  = (int*)alloc((size_t)M0_ * 4);
  int*   OFF0  = (int*)alloc((size_t)M0_ * 4);
  int*   EID0  = (int*)alloc((size_t)NEDGE * 4);
  int*   DEG1  = (int*)alloc((size_t)M1_ * 4);
  int*   OFF1  = (int*)alloc((size_t)M1_ * 4);
  int*   EID1  = (int*)alloc((size_t)NEDGE * 4);

  const int* src0 = ei;
  const int* dst0 = ei + NEDGE;

  hipMemsetAsync(H, 0, G_ * 256 * sizeof(float), stream);
  hipMemsetAsync(SCALE, 0, 12 * sizeof(int), stream);

  // ---- setup ----
  colmax_kernel<<<128, 256, 0, stream>>>(x, SCALE);
  build_wt0_kernel<<<(256 * KPAD_ + 255) / 256, 256, 0, stream>>>(c_wl[0], c_wr[0], SCALE, WT0);
  build_wt12_kernel<<<(2 * 256 * 128 + 255) / 256, 256, 0, stream>>>(c_wl[1], c_wr[1], c_wl[2], c_wr[2], WT1, WT2);

  // ---- layer 0 ----
  csr_graph_kernel<<<G_, 1024, 0, stream>>>(src0, dst0, N0_, DEG0, OFF0, EID0);
  mfma_gemm_kernel<true><<<MPAD0_ / 128, 256, 0, stream>>>(x, nullptr, WT0, YZ, M0_, FEAT_, KPAD_, FEAT_, KPAD_ / 64);
  agg_sage_dots_kernel<<<(M0_ + 3) / 4, 256, 0, stream>>>(YZ, EID0, OFF0, DEG0, c_bl[0], p_wrel[0], p_wroot[0], X, T, R, M0_);
  pool_kernel<1024><<<G_, 1024, 0, stream>>>(X, T, R, p_brel[0], DEG0, OFF0, EID0,
                                             N0_, K0_, NXB, DEG1, OFF1, EID1, H);

  // ---- layer 1 ----
  mfma_gemm_kernel<false><<<MPAD1_ / 128, 256, 0, stream>>>(nullptr, NXB, WT1, YZ, M1_, 128, 128, 128, 2);
  agg_sage_dots_kernel<<<(M1_ + 3) / 4, 256, 0, stream>>>(YZ, EID1, OFF1, DEG1, c_bl[1], p_wrel[1], p_wroot[1], X, T, R, M1_);
  pool_kernel<256><<<G_, 1024, 0, stream>>>(X, T, R, p_brel[1], DEG1, OFF1, EID1,
                                            K0_, K1_, NXB, DEG0, OFF0, EID0, H);

  // ---- layer 2 ----
  mfma_gemm_kernel<false><<<MPAD2_ / 128, 256, 0, stream>>>(nullptr, NXB, WT2, YZ, M2_, 128, 128, 128, 2);
  agg_sage_dots_kernel<<<(M2_ + 3) / 4, 256, 0, stream>>>(YZ, EID0, OFF0, DEG0, c_bl[2], p_wrel[2], p_wroot[2], X, T, R, M2_);
  pool_kernel<64><<<G_, 1024, 0, stream>>>(X, T, R, p_brel[2], DEG0, OFF0, EID0,
                                           K1_, K2_, NXB, nullptr, nullptr, nullptr, H);

  // ---- head ----
  head_kernel<<<1, 256, 0, stream>>>(H, gpp, lin1_w, lin1_b, lin2_w, lin2_b,
                                     grade_w, grade_b, haz_w, haz_b, (float*)d_out);
}